// Round 11
// baseline (1052.843 us; speedup 1.0000x reference)
//
#include <hip/hip_runtime.h>
#include <hip/hip_bf16.h>

// B=512, S=64, IN=128, DM=256, H=8, HD=32, L=2, FF=1024, DO=64, E=8, K=2, GI=8192

typedef __attribute__((ext_vector_type(8))) short bf16x8;
typedef __attribute__((ext_vector_type(4))) float f32x4;

#define DEVINL __device__ __forceinline__
#define MFMA16(a, b, c) __builtin_amdgcn_mfma_f32_16x16x32_bf16((a), (b), (c), 0, 0, 0)

DEVINL float b2f(unsigned short u) {
    unsigned int i = ((unsigned int)u) << 16;
    float f; __builtin_memcpy(&f, &i, 4); return f;
}
DEVINL unsigned short f2b(float f) {
    unsigned int i; __builtin_memcpy(&i, &f, 4);
    unsigned int r = (i + 0x7FFFu + ((i >> 16) & 1u)) >> 16;  // RTN-even
    return (unsigned short)r;
}

// ---------------------------------------------------------------------------
__global__ void zero_cnt_kernel(int* __restrict__ cnt) {
    if (threadIdx.x < 8) cnt[threadIdx.x] = 0;
}

// ---------------------------------------------------------------------------
// convT v2: tiled transpose via LDS. src fp32 [batch][R][C] -> dst bf16
// [batch][C][R]. 64x64 tile: reads coalesced along c, writes coalesced
// along r.
__global__ __launch_bounds__(256) void convT_kernel(
    const float* __restrict__ src, short* __restrict__ dst, int R, int C)
{
    const int tiles_r = R >> 6, tiles_c = C >> 6;
    int t = blockIdx.x;
    const int bM = t / (tiles_r * tiles_c);
    int rem = t - bM * (tiles_r * tiles_c);
    const int tr = rem / tiles_c, tc = rem - tr * tiles_c;
    const int r0 = tr << 6, c0 = tc << 6;
    const float* S = src + (size_t)bM * R * C;
    short* D = dst + (size_t)bM * R * C;
    __shared__ short tile[64][72];
    const int lc = threadIdx.x & 63;
    const int l0 = threadIdx.x >> 6;
    #pragma unroll
    for (int i = 0; i < 16; ++i) {
        int lr = l0 * 16 + i;
        tile[lr][lc] = (short)f2b(S[(size_t)(r0 + lr) * C + c0 + lc]);
    }
    __syncthreads();
    const int lrw = threadIdx.x & 63;
    #pragma unroll
    for (int i = 0; i < 16; ++i) {
        int lcw = l0 * 16 + i;
        D[(size_t)(c0 + lcw) * R + r0 + lrw] = tile[lrw][lcw];
    }
}

// ---------------------------------------------------------------------------
// gate: double-precision logits (stable top-2 vs numpy ref)
__global__ __launch_bounds__(256) void gate_kernel(
    const float* __restrict__ x, const float* __restrict__ Wg, const float* __restrict__ bg,
    int* __restrict__ cnt, int* __restrict__ rlist, float* __restrict__ wlist)
{
    const int b = blockIdx.x;
    const int tid = threadIdx.x;
    const int e8 = tid & 7;
    const int seg = tid >> 3;
    const float* gi = x + (size_t)b * 8192;
    double p = 0.0;
    for (int ii = 0; ii < 256; ++ii) {
        int i = seg * 256 + ii;
        p += (double)gi[i] * (double)Wg[i * 8 + e8];
    }
    p += __shfl_xor(p, 8, 64);
    p += __shfl_xor(p, 16, 64);
    p += __shfl_xor(p, 32, 64);
    __shared__ double wred[4 * 8];
    const int lane = tid & 63, w = tid >> 6;
    if (lane < 8) wred[w * 8 + lane] = p;
    __syncthreads();
    if (tid == 0) {
        double lg[8];
        for (int e = 0; e < 8; ++e)
            lg[e] = wred[e] + wred[8 + e] + wred[16 + e] + wred[24 + e] + (double)bg[e];
        int i1 = 0;
        for (int e = 1; e < 8; ++e) if (lg[e] > lg[i1]) i1 = e;
        int i2 = (i1 == 0) ? 1 : 0;
        for (int e = 0; e < 8; ++e) if (e != i1 && lg[e] > lg[i2]) i2 = e;
        double ex = exp(lg[i2] - lg[i1]);
        float w1 = (float)(1.0 / (1.0 + ex));
        float w2 = (float)(ex / (1.0 + ex));
        int p1 = atomicAdd(&cnt[i1], 1);
        rlist[i1 * 512 + p1] = b; wlist[i1 * 512 + p1] = w1;
        int p2 = atomicAdd(&cnt[i2], 1);
        rlist[i2 * 512 + p2] = b; wlist[i2 * 512 + p2] = w2;
    }
}

// ---------------------------------------------------------------------------
// resproj: 2 batch rows per block, 256 blocks
__global__ __launch_bounds__(256) void resproj_kernel(
    const float* __restrict__ x, const float* __restrict__ Wr, const float* __restrict__ br,
    float* __restrict__ acc_out)
{
    const int b0 = blockIdx.x * 2;
    const int tid = threadIdx.x;
    const int d = tid & 63;
    const int part = tid >> 6;
    float acc0 = 0.f, acc1 = 0.f;
    for (int ii = 0; ii < 2048; ++ii) {
        int i = part * 2048 + ii;
        float wv = Wr[i * 64 + d];
        acc0 += x[(size_t)b0 * 8192 + i] * wv;
        acc1 += x[(size_t)(b0 + 1) * 8192 + i] * wv;
    }
    __shared__ float rr[4][2][64];
    rr[part][0][d] = acc0;
    rr[part][1][d] = acc1;
    __syncthreads();
    if (tid < 128) {
        int k = tid >> 6, dd = tid & 63;
        float v = rr[0][k][dd] + rr[1][k][dd] + rr[2][k][dd] + rr[3][k][dd];
        acc_out[(b0 + k) * 64 + dd] = 0.1f * (v + br[dd]);
    }
}

// ---------------------------------------------------------------------------
// expert kernel — ROUND 11: round 10 still spilled ~73MB. Root cause is the
// ACCUMULATOR class itself: during attention, hr[16](64) + avr[16](64) +
// sc[16](64) = 192 f32x4-class regs before operands -> total ~265 > 256
// unified file. Fix: avr is only ever consumed via f2b() at the hS
// writeback, so carrying it as f32 is waste. Per head compute PV into
// transient avt[8] (32 regs, dies at head end), pack IMMEDIATELY to bf16:
// avb[2][16] u32 (2 bf16/reg) = 32 regs for both heads (was 64). Packing
// applies the same f2b the writeback did -> bit-identical numerics.
// Peak attn set: hr(64)+avb(<=32)+sc(64)+operands(~60) ~= 215 <= 256.
// Everything else identical to round 10 (K-stream, V-first, 78,336 B LDS,
// 2 blocks/CU). XCD pin: e = blockIdx&7.
__global__ __launch_bounds__(256, 2) void expert_kernel(
    const float* __restrict__ x,
    const short* __restrict__ WinT, const float* __restrict__ bin_,
    const short* __restrict__ WqT,  const float* __restrict__ bq,
    const short* __restrict__ WkT,  const float* __restrict__ bk,
    const short* __restrict__ WvT,  const float* __restrict__ bv,
    const short* __restrict__ WoT,  const float* __restrict__ bo,
    const float* __restrict__ ln1g, const float* __restrict__ ln1b,
    const float* __restrict__ ln2g, const float* __restrict__ ln2b,
    const short* __restrict__ W1T,  const float* __restrict__ b1,
    const short* __restrict__ W2T,  const float* __restrict__ b2,
    const float* __restrict__ Wout, const float* __restrict__ bout,
    const int* __restrict__ cnt, const int* __restrict__ rlist,
    const float* __restrict__ wlist, float* __restrict__ acc_out)
{
    const int e = blockIdx.x & 7;          // XCD pin
    const int s = blockIdx.x >> 3;
    if (s >= cnt[e]) return;
    const int b   = rlist[e * 512 + s];
    const float wgt = wlist[e * 512 + s];
    const int tid = threadIdx.x;
    const int lane = tid & 63;
    const int wg  = __builtin_amdgcn_readfirstlane(tid >> 6);
    const int ln = lane & 15, quad = lane >> 4;
    const int nb = wg * 64;                // wave's output-column base

    // LDS: 33,792 + 41,472 + 2,048 + 1,024 = 78,336 B -> 2 blocks/CU
    __shared__ __align__(16) unsigned short hS[64 * 264];     // residual/av/LN out
    __shared__ __align__(16) unsigned short attnS[4 * 5184];  // per-wave attn | xS | tS
    __shared__ float redS[512];                               // LN cross-wave partials
    __shared__ float pooledS[256];
    unsigned short* VTw   = attnS + wg * 5184;  // [32][72] V^T
    unsigned short* Qw    = VTw + 2304;         // [64][36] Q
    unsigned short* Kpart = VTw + 4608;         // [16][36] K chunk
    unsigned short* PSw   = Qw;                 // [64][36] P half (overlays dead Q)
    unsigned short* xS    = attnS;              // [64][136] (block-shared, P0/P1)

    // ---- P0: stage x[b] -> xS bf16 row-major ----
    {
        const float* xb = x + (size_t)b * 8192;
        #pragma unroll
        for (int i = 0; i < 32; ++i) {
            int id = tid + 256 * i;
            xS[(id >> 7) * 136 + (id & 127)] = f2b(xb[id]);
        }
    }
    __syncthreads();

    f32x4 hr[16];   // residual: wave's 64 rows x 64 cols, [rt*4+ct]

    // ---- P1: h0 = x @ Win + bin (K=128) ----
    {
        const short* BW = WinT + (size_t)e * 32768;
        const float* bp = bin_ + e * 256;
        #pragma unroll
        for (int ct = 0; ct < 4; ++ct) {
            bf16x8 Bf[4];
            #pragma unroll
            for (int kt = 0; kt < 4; ++kt)
                Bf[kt] = *(const bf16x8*)(BW + (size_t)(nb + ct * 16 + ln) * 128 + kt * 32 + quad * 8);
            const float bz = bp[nb + ct * 16 + ln];
            #pragma unroll
            for (int rt = 0; rt < 4; ++rt) {
                bf16x8 Af[4];
                #pragma unroll
                for (int kt = 0; kt < 4; ++kt)
                    Af[kt] = *(const bf16x8*)&xS[(rt * 16 + ln) * 136 + kt * 32 + quad * 8];
                f32x4 c = {bz, bz, bz, bz};
                #pragma unroll
                for (int kt = 0; kt < 4; ++kt) c = MFMA16(Af[kt], Bf[kt], c);
                hr[rt * 4 + ct] = c;
                #pragma unroll
                for (int i = 0; i < 4; ++i)
                    hS[(rt * 16 + quad * 4 + i) * 264 + nb + ct * 16 + ln] = f2b(c[i]);
            }
        }
    }
    __syncthreads();

    // LayerNorm over acc (C-layout); cross-wave via redS; writes hr + hS.
    auto LN = [&](f32x4* a, const float* g, const float* bb) {
        #pragma unroll
        for (int rt = 0; rt < 4; ++rt)
            #pragma unroll
            for (int i = 0; i < 4; ++i) {
                float s1 = 0.f, s2 = 0.f;
                #pragma unroll
                for (int ct = 0; ct < 4; ++ct) { float v = a[rt * 4 + ct][i]; s1 += v; s2 += v * v; }
                s1 += __shfl_xor(s1, 1); s1 += __shfl_xor(s1, 2);
                s1 += __shfl_xor(s1, 4); s1 += __shfl_xor(s1, 8);
                s2 += __shfl_xor(s2, 1); s2 += __shfl_xor(s2, 2);
                s2 += __shfl_xor(s2, 4); s2 += __shfl_xor(s2, 8);
                if (ln == 0) {
                    int row = rt * 16 + quad * 4 + i;
                    redS[row * 8 + wg * 2] = s1;
                    redS[row * 8 + wg * 2 + 1] = s2;
                }
            }
        __syncthreads();
        float gv[4], bv2[4];
        #pragma unroll
        for (int ct = 0; ct < 4; ++ct) { gv[ct] = g[nb + ct * 16 + ln]; bv2[ct] = bb[nb + ct * 16 + ln]; }
        #pragma unroll
        for (int rt = 0; rt < 4; ++rt)
            #pragma unroll
            for (int i = 0; i < 4; ++i) {
                int row = rt * 16 + quad * 4 + i;
                float S1 = redS[row * 8 + 0] + redS[row * 8 + 2] + redS[row * 8 + 4] + redS[row * 8 + 6];
                float S2 = redS[row * 8 + 1] + redS[row * 8 + 3] + redS[row * 8 + 5] + redS[row * 8 + 7];
                float m_ = S1 * (1.f / 256.f);
                float rstd = rsqrtf(S2 * (1.f / 256.f) - m_ * m_ + 1e-5f);
                #pragma unroll
                for (int ct = 0; ct < 4; ++ct) {
                    float v = (a[rt * 4 + ct][i] - m_) * rstd * gv[ct] + bv2[ct];
                    hr[rt * 4 + ct][i] = v;
                    hS[row * 264 + nb + ct * 16 + ln] = f2b(v);
                }
            }
        __syncthreads();
    };

    for (int l = 0; l < 2; ++l) {
        const int el = e * 2 + l;
        const short* WqE = WqT + (size_t)el * 65536;
        const short* WkE = WkT + (size_t)el * 65536;
        const short* WvE = WvT + (size_t)el * 65536;
        const short* WoE = WoT + (size_t)el * 65536;
        const short* W1E = W1T + (size_t)el * 262144;
        const short* W2E = W2T + (size_t)el * 262144;
        const float* bq_p = bq + el * 256;
        const float* bk_p = bk + el * 256;
        const float* bv_p = bv + el * 256;
        const float* bo_p = bo + el * 256;

        unsigned int avb[2][16];  // packed bf16 av, [hp][(rt*2+ct2)*2 + i/2]

        // ---- QKV + attention, fully wave-private (no barriers inside) ----
        #pragma unroll
        for (int hp = 0; hp < 2; ++hp) {
            const int hb = nb + hp * 32;   // head (2wg+hp) col base

            // --- V GEMM -> VTw [32][72] (sc not live here) ---
            #pragma unroll
            for (int ct2 = 0; ct2 < 2; ++ct2) {
                bf16x8 Bq[8];
                #pragma unroll
                for (int kt = 0; kt < 8; ++kt)
                    Bq[kt] = *(const bf16x8*)(WvE + (size_t)(hb + ct2 * 16 + ln) * 256 + kt * 32 + quad * 8);
                const float bz2 = bv_p[hb + ct2 * 16 + ln];
                #pragma unroll
                for (int rt = 0; rt < 4; ++rt) {
                    bf16x8 Af[8];
                    #pragma unroll
                    for (int kt = 0; kt < 8; ++kt)
                        Af[kt] = *(const bf16x8*)&hS[(rt * 16 + ln) * 264 + kt * 32 + quad * 8];
                    f32x4 c = {bz2, bz2, bz2, bz2};
                    #pragma unroll
                    for (int kt = 0; kt < 8; ++kt) c = MFMA16(Af[kt], Bq[kt], c);
                    #pragma unroll
                    for (int i = 0; i < 4; ++i)
                        VTw[(ct2 * 16 + ln) * 72 + rt * 16 + quad * 4 + i] = f2b(c[i]);
                }
            }

            // --- Q GEMM -> Qw [64][36] ---
            #pragma unroll
            for (int ct2 = 0; ct2 < 2; ++ct2) {
                bf16x8 Bq[8];
                #pragma unroll
                for (int kt = 0; kt < 8; ++kt)
                    Bq[kt] = *(const bf16x8*)(WqE + (size_t)(hb + ct2 * 16 + ln) * 256 + kt * 32 + quad * 8);
                const float bz2 = bq_p[hb + ct2 * 16 + ln];
                #pragma unroll
                for (int rt = 0; rt < 4; ++rt) {
                    bf16x8 Af[8];
                    #pragma unroll
                    for (int kt = 0; kt < 8; ++kt)
                        Af[kt] = *(const bf16x8*)&hS[(rt * 16 + ln) * 264 + kt * 32 + quad * 8];
                    f32x4 c = {bz2, bz2, bz2, bz2};
                    #pragma unroll
                    for (int kt = 0; kt < 8; ++kt) c = MFMA16(Af[kt], Bq[kt], c);
                    #pragma unroll
                    for (int i = 0; i < 4; ++i)
                        Qw[(rt * 16 + quad * 4 + i) * 36 + ct2 * 16 + ln] = f2b(c[i]);
                }
            }

            // --- K streamed in 16-row chunks: K-chunk GEMM + QK^T partial ---
            f32x4 sc[16];
            {
                float bkz[2];
                #pragma unroll
                for (int ct2 = 0; ct2 < 2; ++ct2) bkz[ct2] = bk_p[hb + ct2 * 16 + ln];
                #pragma unroll
                for (int ck = 0; ck < 4; ++ck) {
                    // K rows ck*16..+15  (= h rows; A-frag rows ck*16+ln)
                    bf16x8 Af[8];
                    #pragma unroll
                    for (int kt = 0; kt < 8; ++kt)
                        Af[kt] = *(const bf16x8*)&hS[(ck * 16 + ln) * 264 + kt * 32 + quad * 8];
                    #pragma unroll
                    for (int ct2 = 0; ct2 < 2; ++ct2) {
                        bf16x8 WkB[8];
                        #pragma unroll
                        for (int kt = 0; kt < 8; ++kt)
                            WkB[kt] = *(const bf16x8*)(WkE + (size_t)(hb + ct2 * 16 + ln) * 256 + kt * 32 + quad * 8);
                        f32x4 c = {bkz[ct2], bkz[ct2], bkz[ct2], bkz[ct2]};
                        #pragma unroll
                        for (int kt = 0; kt < 8; ++kt) c = MFMA16(Af[kt], WkB[kt], c);
                        #pragma unroll
                        for (int i = 0; i < 4; ++i)
                            Kpart[(quad * 4 + i) * 36 + ct2 * 16 + ln] = f2b(c[i]);
                    }
                    // QK^T partial: S cols ck*16..+15 (Kpart row ln, k=quad*8)
                    bf16x8 Bk = *(const bf16x8*)&Kpart[ln * 36 + quad * 8];
                    #pragma unroll
                    for (int rt = 0; rt < 4; ++rt) {
                        bf16x8 Aq = *(const bf16x8*)&Qw[(rt * 16 + ln) * 36 + quad * 8];
                        f32x4 z = {0.f, 0.f, 0.f, 0.f};
                        sc[rt * 4 + ck] = MFMA16(Aq, Bk, z);
                    }
                }
            }

            // --- softmax, fully normalized in registers ---
            const float sscale = 0.17677669529663687f;  // 1/sqrt(32)
            #pragma unroll
            for (int t = 0; t < 16; ++t)
                #pragma unroll
                for (int i = 0; i < 4; ++i) sc[t][i] *= sscale;
            #pragma unroll
            for (int rt = 0; rt < 4; ++rt)
                #pragma unroll
                for (int i = 0; i < 4; ++i) {
                    float m_ = fmaxf(fmaxf(sc[rt * 4 + 0][i], sc[rt * 4 + 1][i]),
                                     fmaxf(sc[rt * 4 + 2][i], sc[rt * 4 + 3][i]));
                    m_ = fmaxf(m_, __shfl_xor(m_, 1));
                    m_ = fmaxf(m_, __shfl_xor(m_, 2));
                    m_ = fmaxf(m_, __shfl_xor(m_, 4));
                    m_ = fmaxf(m_, __shfl_xor(m_, 8));
                    float s_ = 0.f;
                    #pragma unroll
                    for (int ck = 0; ck < 4; ++ck) {
                        sc[rt * 4 + ck][i] = __expf(sc[rt * 4 + ck][i] - m_);
                        s_ += sc[rt * 4 + ck][i];
                    }
                    s_ += __shfl_xor(s_, 1); s_ += __shfl_xor(s_, 2);
                    s_ += __shfl_xor(s_, 4); s_ += __shfl_xor(s_, 8);
                    float inv = 1.f / s_;
                    #pragma unroll
                    for (int ck = 0; ck < 4; ++ck) sc[rt * 4 + ck][i] *= inv;
                }

            // --- two-pass P write (PSw [64][36] overlays dead Q) + PV halves ---
            f32x4 avt[8];   // this head's av, transient
            // pass 0: P cols 0..31
            #pragma unroll
            for (int rt = 0; rt < 4; ++rt)
                #pragma unroll
                for (int i = 0; i < 4; ++i)
                    #pragma unroll
                    for (int ck = 0; ck < 2; ++ck)
                        PSw[(rt * 16 + quad * 4 + i) * 36 + ck * 16 + ln] = f2b(sc[rt * 4 + ck][i]);
            {
                bf16x8 Bv0[2];
                #pragma unroll
                for (int ct2 = 0; ct2 < 2; ++ct2)
                    Bv0[ct2] = *(const bf16x8*)&VTw[(ct2 * 16 + ln) * 72 + quad * 8];
                #pragma unroll
                for (int rt = 0; rt < 4; ++rt) {
                    bf16x8 Ap = *(const bf16x8*)&PSw[(rt * 16 + ln) * 36 + quad * 8];
                    #pragma unroll
                    for (int ct2 = 0; ct2 < 2; ++ct2) {
                        f32x4 z = {0.f, 0.f, 0.f, 0.f};
                        avt[rt * 2 + ct2] = MFMA16(Ap, Bv0[ct2], z);
                    }
                }
            }
            // pass 1: P cols 32..63 (overwrite; in-order LDS, same-wave alias kept)
            #pragma unroll
            for (int rt = 0; rt < 4; ++rt)
                #pragma unroll
                for (int i = 0; i < 4; ++i)
                    #pragma unroll
                    for (int ck = 2; ck < 4; ++ck)
                        PSw[(rt * 16 + quad * 4 + i) * 36 + (ck - 2) * 16 + ln] = f2b(sc[rt * 4 + ck][i]);
            {
                bf16x8 Bv1[2];
                #pragma unroll
                for (int ct2 = 0; ct2 < 2; ++ct2)
                    Bv1[ct2] = *(const bf16x8*)&VTw[(ct2 * 16 + ln) * 72 + 32 + quad * 8];
                #pragma unroll
                for (int rt = 0; rt < 4; ++rt) {
                    bf16x8 Ap = *(const bf16x8*)&PSw[(rt * 16 + ln) * 36 + quad * 8];
                    #pragma unroll
                    for (int ct2 = 0; ct2 < 2; ++ct2)
                        avt[rt * 2 + ct2] = MFMA16(Ap, Bv1[ct2], avt[rt * 2 + ct2]);
                }
            }
            // pack this head's av to bf16 pairs (same f2b the writeback used)
            #pragma unroll
            for (int rt = 0; rt < 4; ++rt)
                #pragma unroll
                for (int ct2 = 0; ct2 < 2; ++ct2) {
                    f32x4 c = avt[rt * 2 + ct2];
                    avb[hp][(rt * 2 + ct2) * 2 + 0] =
                        (unsigned int)f2b(c[0]) | ((unsigned int)f2b(c[1]) << 16);
                    avb[hp][(rt * 2 + ct2) * 2 + 1] =
                        (unsigned int)f2b(c[2]) | ((unsigned int)f2b(c[3]) << 16);
                }
        }

        __syncthreads();   // all waves done reading hS(h)
        // write av (wave's exact 64-col strip) -> hS  (unpack packed bf16)
        #pragma unroll
        for (int hp = 0; hp < 2; ++hp)
            #pragma unroll
            for (int rt = 0; rt < 4; ++rt)
                #pragma unroll
                for (int ct2 = 0; ct2 < 2; ++ct2)
                    #pragma unroll
                    for (int i = 0; i < 4; ++i) {
                        unsigned int w = avb[hp][(rt * 2 + ct2) * 2 + (i >> 1)];
                        unsigned short v = (i & 1) ? (unsigned short)(w >> 16)
                                                   : (unsigned short)(w & 0xFFFFu);
                        hS[(rt * 16 + quad * 4 + i) * 264 + nb + hp * 32 + ct2 * 16 + ln] = v;
                    }
        __syncthreads();

        // ---- O-proj: oacc = h + bo + av @ Wo (K=256) ----
        f32x4 oacc[16];
        #pragma unroll
        for (int rt = 0; rt < 4; ++rt)
            #pragma unroll
            for (int ct = 0; ct < 4; ++ct) {
                float bz = bo_p[nb + ct * 16 + ln];
                f32x4 t = hr[rt * 4 + ct];
                t[0] += bz; t[1] += bz; t[2] += bz; t[3] += bz;
                oacc[rt * 4 + ct] = t;
            }
        #pragma unroll
        for (int ct = 0; ct < 4; ++ct) {
            bf16x8 Bo[8];
            #pragma unroll
            for (int kt = 0; kt < 8; ++kt)
                Bo[kt] = *(const bf16x8*)(WoE + (size_t)(nb + ct * 16 + ln) * 256 + kt * 32 + quad * 8);
            #pragma unroll
            for (int rt = 0; rt < 4; ++rt) {
                bf16x8 Ao[8];
                #pragma unroll
                for (int kt = 0; kt < 8; ++kt)
                    Ao[kt] = *(const bf16x8*)&hS[(rt * 16 + ln) * 264 + kt * 32 + quad * 8];
                #pragma unroll
                for (int kt = 0; kt < 8; ++kt)
                    oacc[rt * 4 + ct] = MFMA16(Ao[kt], Bo[kt], oacc[rt * 4 + ct]);
            }
        }

        // ---- LN1 -> hr, hS ----
        LN(oacc, ln1g + el * 256, ln1b + el * 256);

        // ---- FF: 8 chunks of 128 FF cols, tS double-buffered (1 barrier/chunk) ----
        f32x4 facc[16];
        {
            const float* b2_p = b2 + el * 256;
            #pragma unroll
            for (int rt = 0; rt < 4; ++rt)
                #pragma unroll
                for (int ct = 0; ct < 4; ++ct) {
                    float bz = b2_p[nb + ct * 16 + ln];
                    f32x4 t = hr[rt * 4 + ct];
                    t[0] += bz; t[1] += bz; t[2] += bz; t[3] += bz;
                    facc[rt * 4 + ct] = t;
                }
        }
        const float* b1_p = b1 + el * 1024;
        for (int ch = 0; ch < 8; ++ch) {
            const int fb = ch * 128 + wg * 32;       // wave's 32 FF cols this chunk
            unsigned short* tC = attnS + (ch & 1) * 8704;   // [64][136] dbuf
            #pragma unroll
            for (int ct2 = 0; ct2 < 2; ++ct2) {
                bf16x8 B1c[8];
                #pragma unroll
                for (int kt = 0; kt < 8; ++kt)
                    B1c[kt] = *(const bf16x8*)(W1E + (size_t)(fb + ct2 * 16 + ln) * 256 + kt * 32 + quad * 8);
                const float bz2 = b1_p[fb + ct2 * 16 + ln];
                #pragma unroll
                for (int rt = 0; rt < 4; ++rt) {
                    bf16x8 Af[8];
                    #pragma unroll
                    for (int kt = 0; kt < 8; ++kt)
                        Af[kt] = *(const bf16x8*)&hS[(rt * 16 + ln) * 264 + kt * 32 + quad * 8];
                    f32x4 c = {bz2, bz2, bz2, bz2};
                    #pragma unroll
                    for (int kt = 0; kt < 8; ++kt) c = MFMA16(Af[kt], B1c[kt], c);
                    #pragma unroll
                    for (int i = 0; i < 4; ++i)
                        tC[(rt * 16 + quad * 4 + i) * 136 + wg * 32 + ct2 * 16 + ln]
                            = f2b(fmaxf(c[i], 0.f));
                }
            }
            __syncthreads();
            // W2 partial: K=128
            #pragma unroll
            for (int ct = 0; ct < 4; ++ct) {
                bf16x8 B2c[4];
                #pragma unroll
                for (int kt2 = 0; kt2 < 4; ++kt2)
                    B2c[kt2] = *(const bf16x8*)(W2E + (size_t)(nb + ct * 16 + ln) * 1024 + ch * 128 + kt2 * 32 + quad * 8);
                #pragma unroll
                for (int rt = 0; rt < 4; ++rt) {
                    bf16x8 At[4];
                    #pragma unroll
                    for (int kt2 = 0; kt2 < 4; ++kt2)
                        At[kt2] = *(const bf16x8*)&tC[(rt * 16 + ln) * 136 + kt2 * 32 + quad * 8];
                    #pragma unroll
                    for (int kt2 = 0; kt2 < 4; ++kt2)
                        facc[rt * 4 + ct] = MFMA16(At[kt2], B2c[kt2], facc[rt * 4 + ct]);
                }
            }
            // no barrier: next W1 writes the other tS buffer
        }

        // ---- LN2 -> hr, hS ----
        LN(facc, ln2g + el * 256, ln2b + el * 256);
    }

    // ---- pooling + Wout + weighted combine ----
    {
        #pragma unroll
        for (int ct = 0; ct < 4; ++ct) {
            float s_ = 0.f;
            #pragma unroll
            for (int rt = 0; rt < 4; ++rt)
                #pragma unroll
                for (int i = 0; i < 4; ++i) s_ += hr[rt * 4 + ct][i];
            s_ += __shfl_xor(s_, 16);
            s_ += __shfl_xor(s_, 32);
            if (quad == 0) pooledS[nb + ct * 16 + ln] = s_ * (1.f / 64.f);
        }
        __syncthreads();
        if (tid < 64) {
            const float* Wout_p = Wout + (size_t)e * (256 * 64);
            float o = bout[e * 64 + tid];
            for (int c = 0; c < 256; ++c) o += pooledS[c] * Wout_p[c * 64 + tid];
            atomicAdd(&acc_out[b * 64 + tid], wgt * o);
        }
    }
}

// ---------------------------------------------------------------------------
__global__ __launch_bounds__(64) void final_ln_kernel(
    const float* __restrict__ acc_out, const float* __restrict__ on_g,
    const float* __restrict__ on_b, float* __restrict__ out)
{
    const int b = blockIdx.x;
    const int d = threadIdx.x;
    float v = acc_out[b * 64 + d];
    float s1 = v, s2 = v * v;
    #pragma unroll
    for (int st = 1; st < 64; st <<= 1) {
        s1 += __shfl_xor(s1, st, 64);
        s2 += __shfl_xor(s2, st, 64);
    }
    float m   = s1 * (1.f / 64.f);
    float var = s2 * (1.f / 64.f) - m * m;
    float rstd = rsqrtf(var + 1e-5f);
    out[b * 64 + d] = (v - m) * rstd * on_g[d] + on_b[d];
}

// ---------------------------------------------------------------------------
extern "C" void kernel_launch(void* const* d_in, const int* in_sizes, int n_in,
                              void* d_out, int out_size, void* d_ws, size_t ws_size,
                              hipStream_t stream)
{
    (void)in_sizes; (void)n_in; (void)out_size; (void)ws_size;
    const float* x    = (const float*)d_in[0];
    const float* Win  = (const float*)d_in[1];
    const float* bin_ = (const float*)d_in[2];
    const float* Wq   = (const float*)d_in[3];
    const float* bq   = (const float*)d_in[4];
    const float* Wk   = (const float*)d_in[5];
    const float* bk   = (const float*)d_in[6];
    const float* Wv   = (const float*)d_in[7];
    const float* bv   = (const float*)d_in[8];
    const float* Wo   = (const float*)d_in[9];
    const float* bo   = (const float*)d_in[10];
    const float* ln1g = (const float*)d_in[11];
    const float* ln1b = (const float*)d_in[12];
    const float* ln2g = (const float*)d_in[13];
    const float* ln2b = (const float*)d_in[14];
    const float* W1   = (const float*)d_in[15];
    const float* b1   = (const float*)d_in[16];
    const float* W2   = (const float*)d_in[17];
    const float* b2   = (const float*)d_in[18];
    const float* Wout = (const float*)d_in[19];
    const float* bout = (const float*)d_in[20];
    const float* Wg   = (const float*)d_in[21];
    const float* bg   = (const float*)d_in[22];
    const float* Wr   = (const float*)d_in[23];
    const float* br   = (const float*)d_in[24];
    const float* on_g = (const float*)d_in[25];
    const float* on_b = (const float*)d_in[26];
    float* out = (float*)d_out;

    // workspace carve-up
    char* ws = (char*)d_ws;
    float* acc_out = (float*)ws;                         // 131,072 B
    int*   cnt     = (int*)(ws + 131072);
    int*   rlist   = (int*)(ws + 131200);                // 16,384 B
    float* wlist   = (float*)(ws + 147584);              // 16,384 B
    short* WinT    = (short*)(ws + 164096);              //   524,288 B
    short* WqT     = (short*)(ws + 688384);              // 2,097,152 B
    short* WkT     = (short*)(ws + 2785536);
    short* WvT     = (short*)(ws + 4882688);
    short* WoT     = (short*)(ws + 6979840);
    short* W1T     = (short*)(ws + 9076992);             // 8,388,608 B
    short* W2T     = (short*)(ws + 17465600);            // 8,388,608 B

    // weight transposition fp32 [R][C] -> bf16 [C][R] (tiled, coalesced)
    convT_kernel<<<64, 256, 0, stream>>>(Win, WinT, 128, 256);     // 8*2*4
    convT_kernel<<<256, 256, 0, stream>>>(Wq, WqT, 256, 256);      // 16*4*4
    convT_kernel<<<256, 256, 0, stream>>>(Wk, WkT, 256, 256);
    convT_kernel<<<256, 256, 0, stream>>>(Wv, WvT, 256, 256);
    convT_kernel<<<256, 256, 0, stream>>>(Wo, WoT, 256, 256);
    convT_kernel<<<1024, 256, 0, stream>>>(W1, W1T, 256, 1024);    // 16*4*16
    convT_kernel<<<1024, 256, 0, stream>>>(W2, W2T, 1024, 256);    // 16*16*4

    zero_cnt_kernel<<<1, 64, 0, stream>>>(cnt);
    gate_kernel<<<512, 256, 0, stream>>>(x, Wg, bg, cnt, rlist, wlist);
    resproj_kernel<<<256, 256, 0, stream>>>(x, Wr, br, acc_out);
    expert_kernel<<<4096, 256, 0, stream>>>(x,
        WinT, bin_, WqT, bq, WkT, bk, WvT, bv, WoT, bo,
        ln1g, ln1b, ln2g, ln2b, W1T, b1, W2T, b2, Wout, bout,
        cnt, rlist, wlist, acc_out);
    final_ln_kernel<<<512, 64, 0, stream>>>(acc_out, on_g, on_b, out);
}

// Round 12
// 1006.057 us; speedup vs baseline: 1.0465x; 1.0465x over previous
//
#include <hip/hip_runtime.h>
#include <hip/hip_bf16.h>

// B=512, S=64, IN=128, DM=256, H=8, HD=32, L=2, FF=1024, DO=64, E=8, K=2, GI=8192

typedef __attribute__((ext_vector_type(8))) short bf16x8;
typedef __attribute__((ext_vector_type(4))) float f32x4;

#define DEVINL __device__ __forceinline__
#define MFMA16(a, b, c) __builtin_amdgcn_mfma_f32_16x16x32_bf16((a), (b), (c), 0, 0, 0)

DEVINL float b2f(unsigned short u) {
    unsigned int i = ((unsigned int)u) << 16;
    float f; __builtin_memcpy(&f, &i, 4); return f;
}
DEVINL unsigned short f2b(float f) {
    unsigned int i; __builtin_memcpy(&i, &f, 4);
    unsigned int r = (i + 0x7FFFu + ((i >> 16) & 1u)) >> 16;  // RTN-even
    return (unsigned short)r;
}

// ---------------------------------------------------------------------------
// fused convT: all 7 weight transposes in ONE launch (was 7 kernels + a
// zero_cnt kernel -> launch serialization ~tens of µs). Block-range dispatch:
//   [0,64)      Win  128x256  (8 mats, 2x4 tiles)
//   [64,320)    Wq   256x256  (16 mats, 4x4 tiles)
//   [320,576)   Wk
//   [576,832)   Wv
//   [832,1088)  Wo
//   [1088,2112) W1   256x1024 (16 mats, 4x16 tiles)
//   [2112,3136) W2  1024x256  (16 mats, 16x4 tiles)
// Block 0 additionally zeroes cnt[8] (stream order covers the dependency).
DEVINL void convT_tile(const float* __restrict__ src, short* __restrict__ dst,
                       int R, int C, int t, int tid)
{
    const int tiles_r = R >> 6, tiles_c = C >> 6;
    const int bM = t / (tiles_r * tiles_c);
    int rem = t - bM * (tiles_r * tiles_c);
    const int tr = rem / tiles_c, tc = rem - tr * tiles_c;
    const int r0 = tr << 6, c0 = tc << 6;
    const float* S = src + (size_t)bM * R * C;
    short* D = dst + (size_t)bM * R * C;
    __shared__ short tile[64][72];
    const int lc = tid & 63;
    const int l0 = tid >> 6;
    #pragma unroll
    for (int i = 0; i < 16; ++i) {
        int lr = l0 * 16 + i;
        tile[lr][lc] = (short)f2b(S[(size_t)(r0 + lr) * C + c0 + lc]);
    }
    __syncthreads();
    #pragma unroll
    for (int i = 0; i < 16; ++i) {
        int lcw = l0 * 16 + i;
        D[(size_t)(c0 + lcw) * R + r0 + lc] = tile[lc][lcw];
    }
}

__global__ __launch_bounds__(256) void convT_fused_kernel(
    const float* __restrict__ Win, short* __restrict__ WinT,
    const float* __restrict__ Wq,  short* __restrict__ WqT,
    const float* __restrict__ Wk,  short* __restrict__ WkT,
    const float* __restrict__ Wv,  short* __restrict__ WvT,
    const float* __restrict__ Wo,  short* __restrict__ WoT,
    const float* __restrict__ W1,  short* __restrict__ W1T,
    const float* __restrict__ W2,  short* __restrict__ W2T,
    int* __restrict__ cnt)
{
    const int tid = threadIdx.x;
    int t = blockIdx.x;
    if (t == 0 && tid < 8) cnt[tid] = 0;
    if (t < 64)        { convT_tile(Win, WinT, 128, 256, t, tid); return; }
    t -= 64;
    if (t < 256)       { convT_tile(Wq, WqT, 256, 256, t, tid); return; }
    t -= 256;
    if (t < 256)       { convT_tile(Wk, WkT, 256, 256, t, tid); return; }
    t -= 256;
    if (t < 256)       { convT_tile(Wv, WvT, 256, 256, t, tid); return; }
    t -= 256;
    if (t < 256)       { convT_tile(Wo, WoT, 256, 256, t, tid); return; }
    t -= 256;
    if (t < 1024)      { convT_tile(W1, W1T, 256, 1024, t, tid); return; }
    t -= 1024;
    convT_tile(W2, W2T, 1024, 256, t, tid);
}

// ---------------------------------------------------------------------------
// gate: double-precision logits (stable top-2 vs numpy ref)
__global__ __launch_bounds__(256) void gate_kernel(
    const float* __restrict__ x, const float* __restrict__ Wg, const float* __restrict__ bg,
    int* __restrict__ cnt, int* __restrict__ rlist, float* __restrict__ wlist)
{
    const int b = blockIdx.x;
    const int tid = threadIdx.x;
    const int e8 = tid & 7;
    const int seg = tid >> 3;
    const float* gi = x + (size_t)b * 8192;
    double p = 0.0;
    for (int ii = 0; ii < 256; ++ii) {
        int i = seg * 256 + ii;
        p += (double)gi[i] * (double)Wg[i * 8 + e8];
    }
    p += __shfl_xor(p, 8, 64);
    p += __shfl_xor(p, 16, 64);
    p += __shfl_xor(p, 32, 64);
    __shared__ double wred[4 * 8];
    const int lane = tid & 63, w = tid >> 6;
    if (lane < 8) wred[w * 8 + lane] = p;
    __syncthreads();
    if (tid == 0) {
        double lg[8];
        for (int e = 0; e < 8; ++e)
            lg[e] = wred[e] + wred[8 + e] + wred[16 + e] + wred[24 + e] + (double)bg[e];
        int i1 = 0;
        for (int e = 1; e < 8; ++e) if (lg[e] > lg[i1]) i1 = e;
        int i2 = (i1 == 0) ? 1 : 0;
        for (int e = 0; e < 8; ++e) if (e != i1 && lg[e] > lg[i2]) i2 = e;
        double ex = exp(lg[i2] - lg[i1]);
        float w1 = (float)(1.0 / (1.0 + ex));
        float w2 = (float)(ex / (1.0 + ex));
        int p1 = atomicAdd(&cnt[i1], 1);
        rlist[i1 * 512 + p1] = b; wlist[i1 * 512 + p1] = w1;
        int p2 = atomicAdd(&cnt[i2], 1);
        rlist[i2 * 512 + p2] = b; wlist[i2 * 512 + p2] = w2;
    }
}

// ---------------------------------------------------------------------------
// resproj: 2 batch rows per block, 256 blocks
__global__ __launch_bounds__(256) void resproj_kernel(
    const float* __restrict__ x, const float* __restrict__ Wr, const float* __restrict__ br,
    float* __restrict__ acc_out)
{
    const int b0 = blockIdx.x * 2;
    const int tid = threadIdx.x;
    const int d = tid & 63;
    const int part = tid >> 6;
    float acc0 = 0.f, acc1 = 0.f;
    for (int ii = 0; ii < 2048; ++ii) {
        int i = part * 2048 + ii;
        float wv = Wr[i * 64 + d];
        acc0 += x[(size_t)b0 * 8192 + i] * wv;
        acc1 += x[(size_t)(b0 + 1) * 8192 + i] * wv;
    }
    __shared__ float rr[4][2][64];
    rr[part][0][d] = acc0;
    rr[part][1][d] = acc1;
    __syncthreads();
    if (tid < 128) {
        int k = tid >> 6, dd = tid & 63;
        float v = rr[0][k][dd] + rr[1][k][dd] + rr[2][k][dd] + rr[3][k][dd];
        acc_out[(b0 + k) * 64 + dd] = 0.1f * (v + br[dd]);
    }
}

// ---------------------------------------------------------------------------
// expert kernel — ROUND 12: REVERT to round-10 source exactly (best measured:
// 754 µs). Round 11's bf16 av-packing regressed (828 µs, spill up) — third
// failed register-model prediction; withdrawn. Residual ~73MB spill is a
// secondary cost (225MB spill reduction bought only ~55 µs in rounds 8->10).
// Structure: 4 waves, 2 blocks/CU (78,336 B LDS), K streamed in 16-row
// chunks (sc-free V GEMM), V-first attention, FF tS double-buffer.
// XCD pin: e = blockIdx&7.
__global__ __launch_bounds__(256, 2) void expert_kernel(
    const float* __restrict__ x,
    const short* __restrict__ WinT, const float* __restrict__ bin_,
    const short* __restrict__ WqT,  const float* __restrict__ bq,
    const short* __restrict__ WkT,  const float* __restrict__ bk,
    const short* __restrict__ WvT,  const float* __restrict__ bv,
    const short* __restrict__ WoT,  const float* __restrict__ bo,
    const float* __restrict__ ln1g, const float* __restrict__ ln1b,
    const float* __restrict__ ln2g, const float* __restrict__ ln2b,
    const short* __restrict__ W1T,  const float* __restrict__ b1,
    const short* __restrict__ W2T,  const float* __restrict__ b2,
    const float* __restrict__ Wout, const float* __restrict__ bout,
    const int* __restrict__ cnt, const int* __restrict__ rlist,
    const float* __restrict__ wlist, float* __restrict__ acc_out)
{
    const int e = blockIdx.x & 7;          // XCD pin
    const int s = blockIdx.x >> 3;
    if (s >= cnt[e]) return;
    const int b   = rlist[e * 512 + s];
    const float wgt = wlist[e * 512 + s];
    const int tid = threadIdx.x;
    const int lane = tid & 63;
    const int wg  = __builtin_amdgcn_readfirstlane(tid >> 6);
    const int ln = lane & 15, quad = lane >> 4;
    const int nb = wg * 64;                // wave's output-column base

    // LDS: 33,792 + 41,472 + 2,048 + 1,024 = 78,336 B -> 2 blocks/CU
    __shared__ __align__(16) unsigned short hS[64 * 264];     // residual/av/LN out
    __shared__ __align__(16) unsigned short attnS[4 * 5184];  // per-wave attn | xS | tS
    __shared__ float redS[512];                               // LN cross-wave partials
    __shared__ float pooledS[256];
    unsigned short* VTw   = attnS + wg * 5184;  // [32][72] V^T
    unsigned short* Qw    = VTw + 2304;         // [64][36] Q
    unsigned short* Kpart = VTw + 4608;         // [16][36] K chunk
    unsigned short* PSw   = Qw;                 // [64][36] P half (overlays dead Q)
    unsigned short* xS    = attnS;              // [64][136] (block-shared, P0/P1)

    // ---- P0: stage x[b] -> xS bf16 row-major ----
    {
        const float* xb = x + (size_t)b * 8192;
        #pragma unroll
        for (int i = 0; i < 32; ++i) {
            int id = tid + 256 * i;
            xS[(id >> 7) * 136 + (id & 127)] = f2b(xb[id]);
        }
    }
    __syncthreads();

    f32x4 hr[16];   // residual: wave's 64 rows x 64 cols, [rt*4+ct]

    // ---- P1: h0 = x @ Win + bin (K=128) ----
    {
        const short* BW = WinT + (size_t)e * 32768;
        const float* bp = bin_ + e * 256;
        #pragma unroll
        for (int ct = 0; ct < 4; ++ct) {
            bf16x8 Bf[4];
            #pragma unroll
            for (int kt = 0; kt < 4; ++kt)
                Bf[kt] = *(const bf16x8*)(BW + (size_t)(nb + ct * 16 + ln) * 128 + kt * 32 + quad * 8);
            const float bz = bp[nb + ct * 16 + ln];
            #pragma unroll
            for (int rt = 0; rt < 4; ++rt) {
                bf16x8 Af[4];
                #pragma unroll
                for (int kt = 0; kt < 4; ++kt)
                    Af[kt] = *(const bf16x8*)&xS[(rt * 16 + ln) * 136 + kt * 32 + quad * 8];
                f32x4 c = {bz, bz, bz, bz};
                #pragma unroll
                for (int kt = 0; kt < 4; ++kt) c = MFMA16(Af[kt], Bf[kt], c);
                hr[rt * 4 + ct] = c;
                #pragma unroll
                for (int i = 0; i < 4; ++i)
                    hS[(rt * 16 + quad * 4 + i) * 264 + nb + ct * 16 + ln] = f2b(c[i]);
            }
        }
    }
    __syncthreads();

    // LayerNorm over acc (C-layout); cross-wave via redS; writes hr + hS.
    auto LN = [&](f32x4* a, const float* g, const float* bb) {
        #pragma unroll
        for (int rt = 0; rt < 4; ++rt)
            #pragma unroll
            for (int i = 0; i < 4; ++i) {
                float s1 = 0.f, s2 = 0.f;
                #pragma unroll
                for (int ct = 0; ct < 4; ++ct) { float v = a[rt * 4 + ct][i]; s1 += v; s2 += v * v; }
                s1 += __shfl_xor(s1, 1); s1 += __shfl_xor(s1, 2);
                s1 += __shfl_xor(s1, 4); s1 += __shfl_xor(s1, 8);
                s2 += __shfl_xor(s2, 1); s2 += __shfl_xor(s2, 2);
                s2 += __shfl_xor(s2, 4); s2 += __shfl_xor(s2, 8);
                if (ln == 0) {
                    int row = rt * 16 + quad * 4 + i;
                    redS[row * 8 + wg * 2] = s1;
                    redS[row * 8 + wg * 2 + 1] = s2;
                }
            }
        __syncthreads();
        float gv[4], bv2[4];
        #pragma unroll
        for (int ct = 0; ct < 4; ++ct) { gv[ct] = g[nb + ct * 16 + ln]; bv2[ct] = bb[nb + ct * 16 + ln]; }
        #pragma unroll
        for (int rt = 0; rt < 4; ++rt)
            #pragma unroll
            for (int i = 0; i < 4; ++i) {
                int row = rt * 16 + quad * 4 + i;
                float S1 = redS[row * 8 + 0] + redS[row * 8 + 2] + redS[row * 8 + 4] + redS[row * 8 + 6];
                float S2 = redS[row * 8 + 1] + redS[row * 8 + 3] + redS[row * 8 + 5] + redS[row * 8 + 7];
                float m_ = S1 * (1.f / 256.f);
                float rstd = rsqrtf(S2 * (1.f / 256.f) - m_ * m_ + 1e-5f);
                #pragma unroll
                for (int ct = 0; ct < 4; ++ct) {
                    float v = (a[rt * 4 + ct][i] - m_) * rstd * gv[ct] + bv2[ct];
                    hr[rt * 4 + ct][i] = v;
                    hS[row * 264 + nb + ct * 16 + ln] = f2b(v);
                }
            }
        __syncthreads();
    };

    for (int l = 0; l < 2; ++l) {
        const int el = e * 2 + l;
        const short* WqE = WqT + (size_t)el * 65536;
        const short* WkE = WkT + (size_t)el * 65536;
        const short* WvE = WvT + (size_t)el * 65536;
        const short* WoE = WoT + (size_t)el * 65536;
        const short* W1E = W1T + (size_t)el * 262144;
        const short* W2E = W2T + (size_t)el * 262144;
        const float* bq_p = bq + el * 256;
        const float* bk_p = bk + el * 256;
        const float* bv_p = bv + el * 256;
        const float* bo_p = bo + el * 256;

        f32x4 avr[16];   // both heads' av: [hp*8 + rt*2 + ct2]

        // ---- QKV + attention, fully wave-private (no barriers inside) ----
        #pragma unroll
        for (int hp = 0; hp < 2; ++hp) {
            const int hb = nb + hp * 32;   // head (2wg+hp) col base

            // --- V GEMM -> VTw [32][72] (sc not live here) ---
            #pragma unroll
            for (int ct2 = 0; ct2 < 2; ++ct2) {
                bf16x8 Bq[8];
                #pragma unroll
                for (int kt = 0; kt < 8; ++kt)
                    Bq[kt] = *(const bf16x8*)(WvE + (size_t)(hb + ct2 * 16 + ln) * 256 + kt * 32 + quad * 8);
                const float bz2 = bv_p[hb + ct2 * 16 + ln];
                #pragma unroll
                for (int rt = 0; rt < 4; ++rt) {
                    bf16x8 Af[8];
                    #pragma unroll
                    for (int kt = 0; kt < 8; ++kt)
                        Af[kt] = *(const bf16x8*)&hS[(rt * 16 + ln) * 264 + kt * 32 + quad * 8];
                    f32x4 c = {bz2, bz2, bz2, bz2};
                    #pragma unroll
                    for (int kt = 0; kt < 8; ++kt) c = MFMA16(Af[kt], Bq[kt], c);
                    #pragma unroll
                    for (int i = 0; i < 4; ++i)
                        VTw[(ct2 * 16 + ln) * 72 + rt * 16 + quad * 4 + i] = f2b(c[i]);
                }
            }

            // --- Q GEMM -> Qw [64][36] ---
            #pragma unroll
            for (int ct2 = 0; ct2 < 2; ++ct2) {
                bf16x8 Bq[8];
                #pragma unroll
                for (int kt = 0; kt < 8; ++kt)
                    Bq[kt] = *(const bf16x8*)(WqE + (size_t)(hb + ct2 * 16 + ln) * 256 + kt * 32 + quad * 8);
                const float bz2 = bq_p[hb + ct2 * 16 + ln];
                #pragma unroll
                for (int rt = 0; rt < 4; ++rt) {
                    bf16x8 Af[8];
                    #pragma unroll
                    for (int kt = 0; kt < 8; ++kt)
                        Af[kt] = *(const bf16x8*)&hS[(rt * 16 + ln) * 264 + kt * 32 + quad * 8];
                    f32x4 c = {bz2, bz2, bz2, bz2};
                    #pragma unroll
                    for (int kt = 0; kt < 8; ++kt) c = MFMA16(Af[kt], Bq[kt], c);
                    #pragma unroll
                    for (int i = 0; i < 4; ++i)
                        Qw[(rt * 16 + quad * 4 + i) * 36 + ct2 * 16 + ln] = f2b(c[i]);
                }
            }

            // --- K streamed in 16-row chunks: K-chunk GEMM + QK^T partial ---
            f32x4 sc[16];
            {
                float bkz[2];
                #pragma unroll
                for (int ct2 = 0; ct2 < 2; ++ct2) bkz[ct2] = bk_p[hb + ct2 * 16 + ln];
                #pragma unroll
                for (int ck = 0; ck < 4; ++ck) {
                    // K rows ck*16..+15  (= h rows; A-frag rows ck*16+ln)
                    bf16x8 Af[8];
                    #pragma unroll
                    for (int kt = 0; kt < 8; ++kt)
                        Af[kt] = *(const bf16x8*)&hS[(ck * 16 + ln) * 264 + kt * 32 + quad * 8];
                    #pragma unroll
                    for (int ct2 = 0; ct2 < 2; ++ct2) {
                        bf16x8 WkB[8];
                        #pragma unroll
                        for (int kt = 0; kt < 8; ++kt)
                            WkB[kt] = *(const bf16x8*)(WkE + (size_t)(hb + ct2 * 16 + ln) * 256 + kt * 32 + quad * 8);
                        f32x4 c = {bkz[ct2], bkz[ct2], bkz[ct2], bkz[ct2]};
                        #pragma unroll
                        for (int kt = 0; kt < 8; ++kt) c = MFMA16(Af[kt], WkB[kt], c);
                        #pragma unroll
                        for (int i = 0; i < 4; ++i)
                            Kpart[(quad * 4 + i) * 36 + ct2 * 16 + ln] = f2b(c[i]);
                    }
                    // QK^T partial: S cols ck*16..+15 (Kpart row ln, k=quad*8)
                    bf16x8 Bk = *(const bf16x8*)&Kpart[ln * 36 + quad * 8];
                    #pragma unroll
                    for (int rt = 0; rt < 4; ++rt) {
                        bf16x8 Aq = *(const bf16x8*)&Qw[(rt * 16 + ln) * 36 + quad * 8];
                        f32x4 z = {0.f, 0.f, 0.f, 0.f};
                        sc[rt * 4 + ck] = MFMA16(Aq, Bk, z);
                    }
                }
            }

            // --- softmax, fully normalized in registers ---
            const float sscale = 0.17677669529663687f;  // 1/sqrt(32)
            #pragma unroll
            for (int t = 0; t < 16; ++t)
                #pragma unroll
                for (int i = 0; i < 4; ++i) sc[t][i] *= sscale;
            #pragma unroll
            for (int rt = 0; rt < 4; ++rt)
                #pragma unroll
                for (int i = 0; i < 4; ++i) {
                    float m_ = fmaxf(fmaxf(sc[rt * 4 + 0][i], sc[rt * 4 + 1][i]),
                                     fmaxf(sc[rt * 4 + 2][i], sc[rt * 4 + 3][i]));
                    m_ = fmaxf(m_, __shfl_xor(m_, 1));
                    m_ = fmaxf(m_, __shfl_xor(m_, 2));
                    m_ = fmaxf(m_, __shfl_xor(m_, 4));
                    m_ = fmaxf(m_, __shfl_xor(m_, 8));
                    float s_ = 0.f;
                    #pragma unroll
                    for (int ck = 0; ck < 4; ++ck) {
                        sc[rt * 4 + ck][i] = __expf(sc[rt * 4 + ck][i] - m_);
                        s_ += sc[rt * 4 + ck][i];
                    }
                    s_ += __shfl_xor(s_, 1); s_ += __shfl_xor(s_, 2);
                    s_ += __shfl_xor(s_, 4); s_ += __shfl_xor(s_, 8);
                    float inv = 1.f / s_;
                    #pragma unroll
                    for (int ck = 0; ck < 4; ++ck) sc[rt * 4 + ck][i] *= inv;
                }

            // --- two-pass P write (PSw [64][36] overlays dead Q) + PV halves ---
            // pass 0: P cols 0..31
            #pragma unroll
            for (int rt = 0; rt < 4; ++rt)
                #pragma unroll
                for (int i = 0; i < 4; ++i)
                    #pragma unroll
                    for (int ck = 0; ck < 2; ++ck)
                        PSw[(rt * 16 + quad * 4 + i) * 36 + ck * 16 + ln] = f2b(sc[rt * 4 + ck][i]);
            {
                bf16x8 Bv0[2];
                #pragma unroll
                for (int ct2 = 0; ct2 < 2; ++ct2)
                    Bv0[ct2] = *(const bf16x8*)&VTw[(ct2 * 16 + ln) * 72 + quad * 8];
                #pragma unroll
                for (int rt = 0; rt < 4; ++rt) {
                    bf16x8 Ap = *(const bf16x8*)&PSw[(rt * 16 + ln) * 36 + quad * 8];
                    #pragma unroll
                    for (int ct2 = 0; ct2 < 2; ++ct2) {
                        f32x4 z = {0.f, 0.f, 0.f, 0.f};
                        avr[hp * 8 + rt * 2 + ct2] = MFMA16(Ap, Bv0[ct2], z);
                    }
                }
            }
            // pass 1: P cols 32..63 (overwrite; in-order LDS, same-wave alias kept)
            #pragma unroll
            for (int rt = 0; rt < 4; ++rt)
                #pragma unroll
                for (int i = 0; i < 4; ++i)
                    #pragma unroll
                    for (int ck = 2; ck < 4; ++ck)
                        PSw[(rt * 16 + quad * 4 + i) * 36 + (ck - 2) * 16 + ln] = f2b(sc[rt * 4 + ck][i]);
            {
                bf16x8 Bv1[2];
                #pragma unroll
                for (int ct2 = 0; ct2 < 2; ++ct2)
                    Bv1[ct2] = *(const bf16x8*)&VTw[(ct2 * 16 + ln) * 72 + 32 + quad * 8];
                #pragma unroll
                for (int rt = 0; rt < 4; ++rt) {
                    bf16x8 Ap = *(const bf16x8*)&PSw[(rt * 16 + ln) * 36 + quad * 8];
                    #pragma unroll
                    for (int ct2 = 0; ct2 < 2; ++ct2)
                        avr[hp * 8 + rt * 2 + ct2] = MFMA16(Ap, Bv1[ct2], avr[hp * 8 + rt * 2 + ct2]);
                }
            }
        }

        __syncthreads();   // all waves done reading hS(h)
        // write av (wave's exact 64-col strip) -> hS
        #pragma unroll
        for (int hp = 0; hp < 2; ++hp)
            #pragma unroll
            for (int rt = 0; rt < 4; ++rt)
                #pragma unroll
                for (int ct2 = 0; ct2 < 2; ++ct2)
                    #pragma unroll
                    for (int i = 0; i < 4; ++i)
                        hS[(rt * 16 + quad * 4 + i) * 264 + nb + hp * 32 + ct2 * 16 + ln]
                            = f2b(avr[hp * 8 + rt * 2 + ct2][i]);
        __syncthreads();

        // ---- O-proj: oacc = h + bo + av @ Wo (K=256) ----
        f32x4 oacc[16];
        #pragma unroll
        for (int rt = 0; rt < 4; ++rt)
            #pragma unroll
            for (int ct = 0; ct < 4; ++ct) {
                float bz = bo_p[nb + ct * 16 + ln];
                f32x4 t = hr[rt * 4 + ct];
                t[0] += bz; t[1] += bz; t[2] += bz; t[3] += bz;
                oacc[rt * 4 + ct] = t;
            }
        #pragma unroll
        for (int ct = 0; ct < 4; ++ct) {
            bf16x8 Bo[8];
            #pragma unroll
            for (int kt = 0; kt < 8; ++kt)
                Bo[kt] = *(const bf16x8*)(WoE + (size_t)(nb + ct * 16 + ln) * 256 + kt * 32 + quad * 8);
            #pragma unroll
            for (int rt = 0; rt < 4; ++rt) {
                bf16x8 Ao[8];
                #pragma unroll
                for (int kt = 0; kt < 8; ++kt)
                    Ao[kt] = *(const bf16x8*)&hS[(rt * 16 + ln) * 264 + kt * 32 + quad * 8];
                #pragma unroll
                for (int kt = 0; kt < 8; ++kt)
                    oacc[rt * 4 + ct] = MFMA16(Ao[kt], Bo[kt], oacc[rt * 4 + ct]);
            }
        }

        // ---- LN1 -> hr, hS ----
        LN(oacc, ln1g + el * 256, ln1b + el * 256);

        // ---- FF: 8 chunks of 128 FF cols, tS double-buffered (1 barrier/chunk) ----
        f32x4 facc[16];
        {
            const float* b2_p = b2 + el * 256;
            #pragma unroll
            for (int rt = 0; rt < 4; ++rt)
                #pragma unroll
                for (int ct = 0; ct < 4; ++ct) {
                    float bz = b2_p[nb + ct * 16 + ln];
                    f32x4 t = hr[rt * 4 + ct];
                    t[0] += bz; t[1] += bz; t[2] += bz; t[3] += bz;
                    facc[rt * 4 + ct] = t;
                }
        }
        const float* b1_p = b1 + el * 1024;
        for (int ch = 0; ch < 8; ++ch) {
            const int fb = ch * 128 + wg * 32;       // wave's 32 FF cols this chunk
            unsigned short* tC = attnS + (ch & 1) * 8704;   // [64][136] dbuf
            #pragma unroll
            for (int ct2 = 0; ct2 < 2; ++ct2) {
                bf16x8 B1c[8];
                #pragma unroll
                for (int kt = 0; kt < 8; ++kt)
                    B1c[kt] = *(const bf16x8*)(W1E + (size_t)(fb + ct2 * 16 + ln) * 256 + kt * 32 + quad * 8);
                const float bz2 = b1_p[fb + ct2 * 16 + ln];
                #pragma unroll
                for (int rt = 0; rt < 4; ++rt) {
                    bf16x8 Af[8];
                    #pragma unroll
                    for (int kt = 0; kt < 8; ++kt)
                        Af[kt] = *(const bf16x8*)&hS[(rt * 16 + ln) * 264 + kt * 32 + quad * 8];
                    f32x4 c = {bz2, bz2, bz2, bz2};
                    #pragma unroll
                    for (int kt = 0; kt < 8; ++kt) c = MFMA16(Af[kt], B1c[kt], c);
                    #pragma unroll
                    for (int i = 0; i < 4; ++i)
                        tC[(rt * 16 + quad * 4 + i) * 136 + wg * 32 + ct2 * 16 + ln]
                            = f2b(fmaxf(c[i], 0.f));
                }
            }
            __syncthreads();
            // W2 partial: K=128
            #pragma unroll
            for (int ct = 0; ct < 4; ++ct) {
                bf16x8 B2c[4];
                #pragma unroll
                for (int kt2 = 0; kt2 < 4; ++kt2)
                    B2c[kt2] = *(const bf16x8*)(W2E + (size_t)(nb + ct * 16 + ln) * 1024 + ch * 128 + kt2 * 32 + quad * 8);
                #pragma unroll
                for (int rt = 0; rt < 4; ++rt) {
                    bf16x8 At[4];
                    #pragma unroll
                    for (int kt2 = 0; kt2 < 4; ++kt2)
                        At[kt2] = *(const bf16x8*)&tC[(rt * 16 + ln) * 136 + kt2 * 32 + quad * 8];
                    #pragma unroll
                    for (int kt2 = 0; kt2 < 4; ++kt2)
                        facc[rt * 4 + ct] = MFMA16(At[kt2], B2c[kt2], facc[rt * 4 + ct]);
                }
            }
            // no barrier: next W1 writes the other tS buffer
        }

        // ---- LN2 -> hr, hS ----
        LN(facc, ln2g + el * 256, ln2b + el * 256);
    }

    // ---- pooling + Wout + weighted combine ----
    {
        #pragma unroll
        for (int ct = 0; ct < 4; ++ct) {
            float s_ = 0.f;
            #pragma unroll
            for (int rt = 0; rt < 4; ++rt)
                #pragma unroll
                for (int i = 0; i < 4; ++i) s_ += hr[rt * 4 + ct][i];
            s_ += __shfl_xor(s_, 16);
            s_ += __shfl_xor(s_, 32);
            if (quad == 0) pooledS[nb + ct * 16 + ln] = s_ * (1.f / 64.f);
        }
        __syncthreads();
        if (tid < 64) {
            const float* Wout_p = Wout + (size_t)e * (256 * 64);
            float o = bout[e * 64 + tid];
            for (int c = 0; c < 256; ++c) o += pooledS[c] * Wout_p[c * 64 + tid];
            atomicAdd(&acc_out[b * 64 + tid], wgt * o);
        }
    }
}

// ---------------------------------------------------------------------------
__global__ __launch_bounds__(64) void final_ln_kernel(
    const float* __restrict__ acc_out, const float* __restrict__ on_g,
    const float* __restrict__ on_b, float* __restrict__ out)
{
    const int b = blockIdx.x;
    const int d = threadIdx.x;
    float v = acc_out[b * 64 + d];
    float s1 = v, s2 = v * v;
    #pragma unroll
    for (int st = 1; st < 64; st <<= 1) {
        s1 += __shfl_xor(s1, st, 64);
        s2 += __shfl_xor(s2, st, 64);
    }
    float m   = s1 * (1.f / 64.f);
    float var = s2 * (1.f / 64.f) - m * m;
    float rstd = rsqrtf(var + 1e-5f);
    out[b * 64 + d] = (v - m) * rstd * on_g[d] + on_b[d];
}

// ---------------------------------------------------------------------------
extern "C" void kernel_launch(void* const* d_in, const int* in_sizes, int n_in,
                              void* d_out, int out_size, void* d_ws, size_t ws_size,
                              hipStream_t stream)
{
    (void)in_sizes; (void)n_in; (void)out_size; (void)ws_size;
    const float* x    = (const float*)d_in[0];
    const float* Win  = (const float*)d_in[1];
    const float* bin_ = (const float*)d_in[2];
    const float* Wq   = (const float*)d_in[3];
    const float* bq   = (const float*)d_in[4];
    const float* Wk   = (const float*)d_in[5];
    const float* bk   = (const float*)d_in[6];
    const float* Wv   = (const float*)d_in[7];
    const float* bv   = (const float*)d_in[8];
    const float* Wo   = (const float*)d_in[9];
    const float* bo   = (const float*)d_in[10];
    const float* ln1g = (const float*)d_in[11];
    const float* ln1b = (const float*)d_in[12];
    const float* ln2g = (const float*)d_in[13];
    const float* ln2b = (const float*)d_in[14];
    const float* W1   = (const float*)d_in[15];
    const float* b1   = (const float*)d_in[16];
    const float* W2   = (const float*)d_in[17];
    const float* b2   = (const float*)d_in[18];
    const float* Wout = (const float*)d_in[19];
    const float* bout = (const float*)d_in[20];
    const float* Wg   = (const float*)d_in[21];
    const float* bg   = (const float*)d_in[22];
    const float* Wr   = (const float*)d_in[23];
    const float* br   = (const float*)d_in[24];
    const float* on_g = (const float*)d_in[25];
    const float* on_b = (const float*)d_in[26];
    float* out = (float*)d_out;

    // workspace carve-up
    char* ws = (char*)d_ws;
    float* acc_out = (float*)ws;                         // 131,072 B
    int*   cnt     = (int*)(ws + 131072);
    int*   rlist   = (int*)(ws + 131200);                // 16,384 B
    float* wlist   = (float*)(ws + 147584);              // 16,384 B
    short* WinT    = (short*)(ws + 164096);              //   524,288 B
    short* WqT     = (short*)(ws + 688384);              // 2,097,152 B
    short* WkT     = (short*)(ws + 2785536);
    short* WvT     = (short*)(ws + 4882688);
    short* WoT     = (short*)(ws + 6979840);
    short* W1T     = (short*)(ws + 9076992);             // 8,388,608 B
    short* W2T     = (short*)(ws + 17465600);            // 8,388,608 B

    // fused weight transposition + cnt zeroing: 1 launch (was 8)
    convT_fused_kernel<<<3136, 256, 0, stream>>>(
        Win, WinT, Wq, WqT, Wk, WkT, Wv, WvT, Wo, WoT, W1, W1T, W2, W2T, cnt);

    gate_kernel<<<512, 256, 0, stream>>>(x, Wg, bg, cnt, rlist, wlist);
    resproj_kernel<<<256, 256, 0, stream>>>(x, Wr, br, acc_out);
    expert_kernel<<<4096, 256, 0, stream>>>(x,
        WinT, bin_, WqT, bq, WkT, bk, WvT, bv, WoT, bo,
        ln1g, ln1b, ln2g, ln2b, W1T, b1, W2T, b2, Wout, bout,
        cnt, rlist, wlist, acc_out);
    final_ln_kernel<<<512, 64, 0, stream>>>(acc_out, on_g, on_b, out);
}

// Round 13
// 877.457 us; speedup vs baseline: 1.1999x; 1.1466x over previous
//
#include <hip/hip_runtime.h>
#include <hip/hip_bf16.h>

// B=512, S=64, IN=128, DM=256, H=8, HD=32, L=2, FF=1024, DO=64, E=8, K=2, GI=8192

typedef __attribute__((ext_vector_type(8))) short bf16x8;
typedef __attribute__((ext_vector_type(4))) float f32x4;

#define DEVINL __device__ __forceinline__
#define MFMA16(a, b, c) __builtin_amdgcn_mfma_f32_16x16x32_bf16((a), (b), (c), 0, 0, 0)

DEVINL float b2f(unsigned short u) {
    unsigned int i = ((unsigned int)u) << 16;
    float f; __builtin_memcpy(&f, &i, 4); return f;
}
DEVINL unsigned short f2b(float f) {
    unsigned int i; __builtin_memcpy(&i, &f, 4);
    unsigned int r = (i + 0x7FFFu + ((i >> 16) & 1u)) >> 16;  // RTN-even
    return (unsigned short)r;
}

// ---------------------------------------------------------------------------
__global__ void zero_cnt_kernel(int* __restrict__ cnt) {
    if (threadIdx.x < 8) cnt[threadIdx.x] = 0;
}

// ---------------------------------------------------------------------------
// ROUND 13: fused convT + gate + acc_out-zero in ONE launch. gate depends
// only on x/Wg/bg, convT only on weights -> gate's latency-bound fp64 loop
// overlaps convT's streaming instead of running serially after it.
// Block ranges:
//   [0,3136)     convT (7 weight tensors, 64x64 tiles)
//   [3136,3648)  gate  (b = t-3136)
//   [3648,3680)  zero acc_out (32 blocks x 256 thr x 16B = 131072 B)
DEVINL void convT_tile(const float* __restrict__ src, short* __restrict__ dst,
                       int R, int C, int t, int tid, short (*tile)[72])
{
    const int tiles_r = R >> 6, tiles_c = C >> 6;
    const int bM = t / (tiles_r * tiles_c);
    int rem = t - bM * (tiles_r * tiles_c);
    const int tr = rem / tiles_c, tc = rem - tr * tiles_c;
    const int r0 = tr << 6, c0 = tc << 6;
    const float* S = src + (size_t)bM * R * C;
    short* D = dst + (size_t)bM * R * C;
    const int lc = tid & 63;
    const int l0 = tid >> 6;
    #pragma unroll
    for (int i = 0; i < 16; ++i) {
        int lr = l0 * 16 + i;
        tile[lr][lc] = (short)f2b(S[(size_t)(r0 + lr) * C + c0 + lc]);
    }
    __syncthreads();
    #pragma unroll
    for (int i = 0; i < 16; ++i) {
        int lcw = l0 * 16 + i;
        D[(size_t)(c0 + lcw) * R + r0 + lc] = tile[lc][lcw];
    }
}

__global__ __launch_bounds__(256) void prep_fused_kernel(
    const float* __restrict__ Win, short* __restrict__ WinT,
    const float* __restrict__ Wq,  short* __restrict__ WqT,
    const float* __restrict__ Wk,  short* __restrict__ WkT,
    const float* __restrict__ Wv,  short* __restrict__ WvT,
    const float* __restrict__ Wo,  short* __restrict__ WoT,
    const float* __restrict__ W1,  short* __restrict__ W1T,
    const float* __restrict__ W2,  short* __restrict__ W2T,
    const float* __restrict__ x,   const float* __restrict__ Wg,
    const float* __restrict__ bg,  int* __restrict__ cnt,
    int* __restrict__ rlist, float* __restrict__ wlist,
    float* __restrict__ acc_out)
{
    __shared__ short tile[64][72];
    __shared__ double wred[4 * 8];
    const int tid = threadIdx.x;
    int t = blockIdx.x;
    if (t < 64)   { convT_tile(Win, WinT, 128, 256, t, tid, tile); return; }
    t -= 64;
    if (t < 256)  { convT_tile(Wq, WqT, 256, 256, t, tid, tile); return; }
    t -= 256;
    if (t < 256)  { convT_tile(Wk, WkT, 256, 256, t, tid, tile); return; }
    t -= 256;
    if (t < 256)  { convT_tile(Wv, WvT, 256, 256, t, tid, tile); return; }
    t -= 256;
    if (t < 256)  { convT_tile(Wo, WoT, 256, 256, t, tid, tile); return; }
    t -= 256;
    if (t < 1024) { convT_tile(W1, W1T, 256, 1024, t, tid, tile); return; }
    t -= 1024;
    if (t < 1024) { convT_tile(W2, W2T, 1024, 256, t, tid, tile); return; }
    t -= 1024;
    if (t < 512) {
        // ---- gate: double-precision logits (stable top-2 vs numpy ref) ----
        const int b = t;
        const int e8 = tid & 7;
        const int seg = tid >> 3;
        const float* gi = x + (size_t)b * 8192;
        double p = 0.0;
        for (int ii = 0; ii < 256; ++ii) {
            int i = seg * 256 + ii;
            p += (double)gi[i] * (double)Wg[i * 8 + e8];
        }
        p += __shfl_xor(p, 8, 64);
        p += __shfl_xor(p, 16, 64);
        p += __shfl_xor(p, 32, 64);
        const int lane = tid & 63, w = tid >> 6;
        if (lane < 8) wred[w * 8 + lane] = p;
        __syncthreads();
        if (tid == 0) {
            double lg[8];
            for (int e = 0; e < 8; ++e)
                lg[e] = wred[e] + wred[8 + e] + wred[16 + e] + wred[24 + e] + (double)bg[e];
            int i1 = 0;
            for (int e = 1; e < 8; ++e) if (lg[e] > lg[i1]) i1 = e;
            int i2 = (i1 == 0) ? 1 : 0;
            for (int e = 0; e < 8; ++e) if (e != i1 && lg[e] > lg[i2]) i2 = e;
            double ex = exp(lg[i2] - lg[i1]);
            float w1 = (float)(1.0 / (1.0 + ex));
            float w2 = (float)(ex / (1.0 + ex));
            int p1 = atomicAdd(&cnt[i1], 1);
            rlist[i1 * 512 + p1] = b; wlist[i1 * 512 + p1] = w1;
            int p2 = atomicAdd(&cnt[i2], 1);
            rlist[i2 * 512 + p2] = b; wlist[i2 * 512 + p2] = w2;
        }
        return;
    }
    t -= 512;
    // ---- zero acc_out (131,072 B): 32 blocks x 256 thr x 16 B ----
    f32x4 z = {0.f, 0.f, 0.f, 0.f};
    ((f32x4*)acc_out)[t * 256 + tid] = z;
}

// ---------------------------------------------------------------------------
// expert kernel + resproj fused — ROUND 13: blocks [0,4096) = expert
// (round-12 body, unchanged: 754 µs verified structure); blocks
// [4096,4352) = resproj (2 rows/block, atomicAdd into pre-zeroed acc_out;
// commutative with expert's atomics). 3072 of 4096 expert blocks exit
// immediately, so resproj runs CONCURRENTLY on freed CUs instead of as a
// serial prior launch. resproj reuses redS as scratch -> LDS unchanged
// (78,336 B, 2 blocks/CU). XCD pin: e = blockIdx&7.
__global__ __launch_bounds__(256, 2) void expert_kernel(
    const float* __restrict__ x,
    const short* __restrict__ WinT, const float* __restrict__ bin_,
    const short* __restrict__ WqT,  const float* __restrict__ bq,
    const short* __restrict__ WkT,  const float* __restrict__ bk,
    const short* __restrict__ WvT,  const float* __restrict__ bv,
    const short* __restrict__ WoT,  const float* __restrict__ bo,
    const float* __restrict__ ln1g, const float* __restrict__ ln1b,
    const float* __restrict__ ln2g, const float* __restrict__ ln2b,
    const short* __restrict__ W1T,  const float* __restrict__ b1,
    const short* __restrict__ W2T,  const float* __restrict__ b2,
    const float* __restrict__ Wout, const float* __restrict__ bout,
    const float* __restrict__ Wr,   const float* __restrict__ br,
    const int* __restrict__ cnt, const int* __restrict__ rlist,
    const float* __restrict__ wlist, float* __restrict__ acc_out)
{
    // LDS (declared up front; resproj path reuses redS)
    __shared__ __align__(16) unsigned short hS[64 * 264];     // residual/av/LN out
    __shared__ __align__(16) unsigned short attnS[4 * 5184];  // per-wave attn | xS | tS
    __shared__ float redS[512];                               // LN partials / resproj scratch
    __shared__ float pooledS[256];

    const int tid = threadIdx.x;

    if (blockIdx.x >= 4096) {
        // ---- resproj: 2 batch rows per block, atomicAdd into zeroed acc_out ----
        const int b0 = (blockIdx.x - 4096) * 2;
        const int d = tid & 63;
        const int part = tid >> 6;
        float acc0 = 0.f, acc1 = 0.f;
        for (int ii = 0; ii < 2048; ++ii) {
            int i = part * 2048 + ii;
            float wv = Wr[i * 64 + d];
            acc0 += x[(size_t)b0 * 8192 + i] * wv;
            acc1 += x[(size_t)(b0 + 1) * 8192 + i] * wv;
        }
        float (*rr)[2][64] = (float(*)[2][64])redS;
        rr[part][0][d] = acc0;
        rr[part][1][d] = acc1;
        __syncthreads();
        if (tid < 128) {
            int k = tid >> 6, dd = tid & 63;
            float v = rr[0][k][dd] + rr[1][k][dd] + rr[2][k][dd] + rr[3][k][dd];
            atomicAdd(&acc_out[(b0 + k) * 64 + dd], 0.1f * (v + br[dd]));
        }
        return;
    }

    const int e = blockIdx.x & 7;          // XCD pin
    const int s = blockIdx.x >> 3;
    if (s >= cnt[e]) return;
    const int b   = rlist[e * 512 + s];
    const float wgt = wlist[e * 512 + s];
    const int lane = tid & 63;
    const int wg  = __builtin_amdgcn_readfirstlane(tid >> 6);
    const int ln = lane & 15, quad = lane >> 4;
    const int nb = wg * 64;                // wave's output-column base

    unsigned short* VTw   = attnS + wg * 5184;  // [32][72] V^T
    unsigned short* Qw    = VTw + 2304;         // [64][36] Q
    unsigned short* Kpart = VTw + 4608;         // [16][36] K chunk
    unsigned short* PSw   = Qw;                 // [64][36] P half (overlays dead Q)
    unsigned short* xS    = attnS;              // [64][136] (block-shared, P0/P1)

    // ---- P0: stage x[b] -> xS bf16 row-major ----
    {
        const float* xb = x + (size_t)b * 8192;
        #pragma unroll
        for (int i = 0; i < 32; ++i) {
            int id = tid + 256 * i;
            xS[(id >> 7) * 136 + (id & 127)] = f2b(xb[id]);
        }
    }
    __syncthreads();

    f32x4 hr[16];   // residual: wave's 64 rows x 64 cols, [rt*4+ct]

    // ---- P1: h0 = x @ Win + bin (K=128) ----
    {
        const short* BW = WinT + (size_t)e * 32768;
        const float* bp = bin_ + e * 256;
        #pragma unroll
        for (int ct = 0; ct < 4; ++ct) {
            bf16x8 Bf[4];
            #pragma unroll
            for (int kt = 0; kt < 4; ++kt)
                Bf[kt] = *(const bf16x8*)(BW + (size_t)(nb + ct * 16 + ln) * 128 + kt * 32 + quad * 8);
            const float bz = bp[nb + ct * 16 + ln];
            #pragma unroll
            for (int rt = 0; rt < 4; ++rt) {
                bf16x8 Af[4];
                #pragma unroll
                for (int kt = 0; kt < 4; ++kt)
                    Af[kt] = *(const bf16x8*)&xS[(rt * 16 + ln) * 136 + kt * 32 + quad * 8];
                f32x4 c = {bz, bz, bz, bz};
                #pragma unroll
                for (int kt = 0; kt < 4; ++kt) c = MFMA16(Af[kt], Bf[kt], c);
                hr[rt * 4 + ct] = c;
                #pragma unroll
                for (int i = 0; i < 4; ++i)
                    hS[(rt * 16 + quad * 4 + i) * 264 + nb + ct * 16 + ln] = f2b(c[i]);
            }
        }
    }
    __syncthreads();

    // LayerNorm over acc (C-layout); cross-wave via redS; writes hr + hS.
    auto LN = [&](f32x4* a, const float* g, const float* bb) {
        #pragma unroll
        for (int rt = 0; rt < 4; ++rt)
            #pragma unroll
            for (int i = 0; i < 4; ++i) {
                float s1 = 0.f, s2 = 0.f;
                #pragma unroll
                for (int ct = 0; ct < 4; ++ct) { float v = a[rt * 4 + ct][i]; s1 += v; s2 += v * v; }
                s1 += __shfl_xor(s1, 1); s1 += __shfl_xor(s1, 2);
                s1 += __shfl_xor(s1, 4); s1 += __shfl_xor(s1, 8);
                s2 += __shfl_xor(s2, 1); s2 += __shfl_xor(s2, 2);
                s2 += __shfl_xor(s2, 4); s2 += __shfl_xor(s2, 8);
                if (ln == 0) {
                    int row = rt * 16 + quad * 4 + i;
                    redS[row * 8 + wg * 2] = s1;
                    redS[row * 8 + wg * 2 + 1] = s2;
                }
            }
        __syncthreads();
        float gv[4], bv2[4];
        #pragma unroll
        for (int ct = 0; ct < 4; ++ct) { gv[ct] = g[nb + ct * 16 + ln]; bv2[ct] = bb[nb + ct * 16 + ln]; }
        #pragma unroll
        for (int rt = 0; rt < 4; ++rt)
            #pragma unroll
            for (int i = 0; i < 4; ++i) {
                int row = rt * 16 + quad * 4 + i;
                float S1 = redS[row * 8 + 0] + redS[row * 8 + 2] + redS[row * 8 + 4] + redS[row * 8 + 6];
                float S2 = redS[row * 8 + 1] + redS[row * 8 + 3] + redS[row * 8 + 5] + redS[row * 8 + 7];
                float m_ = S1 * (1.f / 256.f);
                float rstd = rsqrtf(S2 * (1.f / 256.f) - m_ * m_ + 1e-5f);
                #pragma unroll
                for (int ct = 0; ct < 4; ++ct) {
                    float v = (a[rt * 4 + ct][i] - m_) * rstd * gv[ct] + bv2[ct];
                    hr[rt * 4 + ct][i] = v;
                    hS[row * 264 + nb + ct * 16 + ln] = f2b(v);
                }
            }
        __syncthreads();
    };

    for (int l = 0; l < 2; ++l) {
        const int el = e * 2 + l;
        const short* WqE = WqT + (size_t)el * 65536;
        const short* WkE = WkT + (size_t)el * 65536;
        const short* WvE = WvT + (size_t)el * 65536;
        const short* WoE = WoT + (size_t)el * 65536;
        const short* W1E = W1T + (size_t)el * 262144;
        const short* W2E = W2T + (size_t)el * 262144;
        const float* bq_p = bq + el * 256;
        const float* bk_p = bk + el * 256;
        const float* bv_p = bv + el * 256;
        const float* bo_p = bo + el * 256;

        f32x4 avr[16];   // both heads' av: [hp*8 + rt*2 + ct2]

        // ---- QKV + attention, fully wave-private (no barriers inside) ----
        #pragma unroll
        for (int hp = 0; hp < 2; ++hp) {
            const int hb = nb + hp * 32;   // head (2wg+hp) col base

            // --- V GEMM -> VTw [32][72] (sc not live here) ---
            #pragma unroll
            for (int ct2 = 0; ct2 < 2; ++ct2) {
                bf16x8 Bq[8];
                #pragma unroll
                for (int kt = 0; kt < 8; ++kt)
                    Bq[kt] = *(const bf16x8*)(WvE + (size_t)(hb + ct2 * 16 + ln) * 256 + kt * 32 + quad * 8);
                const float bz2 = bv_p[hb + ct2 * 16 + ln];
                #pragma unroll
                for (int rt = 0; rt < 4; ++rt) {
                    bf16x8 Af[8];
                    #pragma unroll
                    for (int kt = 0; kt < 8; ++kt)
                        Af[kt] = *(const bf16x8*)&hS[(rt * 16 + ln) * 264 + kt * 32 + quad * 8];
                    f32x4 c = {bz2, bz2, bz2, bz2};
                    #pragma unroll
                    for (int kt = 0; kt < 8; ++kt) c = MFMA16(Af[kt], Bq[kt], c);
                    #pragma unroll
                    for (int i = 0; i < 4; ++i)
                        VTw[(ct2 * 16 + ln) * 72 + rt * 16 + quad * 4 + i] = f2b(c[i]);
                }
            }

            // --- Q GEMM -> Qw [64][36] ---
            #pragma unroll
            for (int ct2 = 0; ct2 < 2; ++ct2) {
                bf16x8 Bq[8];
                #pragma unroll
                for (int kt = 0; kt < 8; ++kt)
                    Bq[kt] = *(const bf16x8*)(WqE + (size_t)(hb + ct2 * 16 + ln) * 256 + kt * 32 + quad * 8);
                const float bz2 = bq_p[hb + ct2 * 16 + ln];
                #pragma unroll
                for (int rt = 0; rt < 4; ++rt) {
                    bf16x8 Af[8];
                    #pragma unroll
                    for (int kt = 0; kt < 8; ++kt)
                        Af[kt] = *(const bf16x8*)&hS[(rt * 16 + ln) * 264 + kt * 32 + quad * 8];
                    f32x4 c = {bz2, bz2, bz2, bz2};
                    #pragma unroll
                    for (int kt = 0; kt < 8; ++kt) c = MFMA16(Af[kt], Bq[kt], c);
                    #pragma unroll
                    for (int i = 0; i < 4; ++i)
                        Qw[(rt * 16 + quad * 4 + i) * 36 + ct2 * 16 + ln] = f2b(c[i]);
                }
            }

            // --- K streamed in 16-row chunks: K-chunk GEMM + QK^T partial ---
            f32x4 sc[16];
            {
                float bkz[2];
                #pragma unroll
                for (int ct2 = 0; ct2 < 2; ++ct2) bkz[ct2] = bk_p[hb + ct2 * 16 + ln];
                #pragma unroll
                for (int ck = 0; ck < 4; ++ck) {
                    // K rows ck*16..+15  (= h rows; A-frag rows ck*16+ln)
                    bf16x8 Af[8];
                    #pragma unroll
                    for (int kt = 0; kt < 8; ++kt)
                        Af[kt] = *(const bf16x8*)&hS[(ck * 16 + ln) * 264 + kt * 32 + quad * 8];
                    #pragma unroll
                    for (int ct2 = 0; ct2 < 2; ++ct2) {
                        bf16x8 WkB[8];
                        #pragma unroll
                        for (int kt = 0; kt < 8; ++kt)
                            WkB[kt] = *(const bf16x8*)(WkE + (size_t)(hb + ct2 * 16 + ln) * 256 + kt * 32 + quad * 8);
                        f32x4 c = {bkz[ct2], bkz[ct2], bkz[ct2], bkz[ct2]};
                        #pragma unroll
                        for (int kt = 0; kt < 8; ++kt) c = MFMA16(Af[kt], WkB[kt], c);
                        #pragma unroll
                        for (int i = 0; i < 4; ++i)
                            Kpart[(quad * 4 + i) * 36 + ct2 * 16 + ln] = f2b(c[i]);
                    }
                    // QK^T partial: S cols ck*16..+15 (Kpart row ln, k=quad*8)
                    bf16x8 Bk = *(const bf16x8*)&Kpart[ln * 36 + quad * 8];
                    #pragma unroll
                    for (int rt = 0; rt < 4; ++rt) {
                        bf16x8 Aq = *(const bf16x8*)&Qw[(rt * 16 + ln) * 36 + quad * 8];
                        f32x4 z = {0.f, 0.f, 0.f, 0.f};
                        sc[rt * 4 + ck] = MFMA16(Aq, Bk, z);
                    }
                }
            }

            // --- softmax, fully normalized in registers ---
            const float sscale = 0.17677669529663687f;  // 1/sqrt(32)
            #pragma unroll
            for (int t = 0; t < 16; ++t)
                #pragma unroll
                for (int i = 0; i < 4; ++i) sc[t][i] *= sscale;
            #pragma unroll
            for (int rt = 0; rt < 4; ++rt)
                #pragma unroll
                for (int i = 0; i < 4; ++i) {
                    float m_ = fmaxf(fmaxf(sc[rt * 4 + 0][i], sc[rt * 4 + 1][i]),
                                     fmaxf(sc[rt * 4 + 2][i], sc[rt * 4 + 3][i]));
                    m_ = fmaxf(m_, __shfl_xor(m_, 1));
                    m_ = fmaxf(m_, __shfl_xor(m_, 2));
                    m_ = fmaxf(m_, __shfl_xor(m_, 4));
                    m_ = fmaxf(m_, __shfl_xor(m_, 8));
                    float s_ = 0.f;
                    #pragma unroll
                    for (int ck = 0; ck < 4; ++ck) {
                        sc[rt * 4 + ck][i] = __expf(sc[rt * 4 + ck][i] - m_);
                        s_ += sc[rt * 4 + ck][i];
                    }
                    s_ += __shfl_xor(s_, 1); s_ += __shfl_xor(s_, 2);
                    s_ += __shfl_xor(s_, 4); s_ += __shfl_xor(s_, 8);
                    float inv = 1.f / s_;
                    #pragma unroll
                    for (int ck = 0; ck < 4; ++ck) sc[rt * 4 + ck][i] *= inv;
                }

            // --- two-pass P write (PSw [64][36] overlays dead Q) + PV halves ---
            // pass 0: P cols 0..31
            #pragma unroll
            for (int rt = 0; rt < 4; ++rt)
                #pragma unroll
                for (int i = 0; i < 4; ++i)
                    #pragma unroll
                    for (int ck = 0; ck < 2; ++ck)
                        PSw[(rt * 16 + quad * 4 + i) * 36 + ck * 16 + ln] = f2b(sc[rt * 4 + ck][i]);
            {
                bf16x8 Bv0[2];
                #pragma unroll
                for (int ct2 = 0; ct2 < 2; ++ct2)
                    Bv0[ct2] = *(const bf16x8*)&VTw[(ct2 * 16 + ln) * 72 + quad * 8];
                #pragma unroll
                for (int rt = 0; rt < 4; ++rt) {
                    bf16x8 Ap = *(const bf16x8*)&PSw[(rt * 16 + ln) * 36 + quad * 8];
                    #pragma unroll
                    for (int ct2 = 0; ct2 < 2; ++ct2) {
                        f32x4 z = {0.f, 0.f, 0.f, 0.f};
                        avr[hp * 8 + rt * 2 + ct2] = MFMA16(Ap, Bv0[ct2], z);
                    }
                }
            }
            // pass 1: P cols 32..63 (overwrite; in-order LDS, same-wave alias kept)
            #pragma unroll
            for (int rt = 0; rt < 4; ++rt)
                #pragma unroll
                for (int i = 0; i < 4; ++i)
                    #pragma unroll
                    for (int ck = 2; ck < 4; ++ck)
                        PSw[(rt * 16 + quad * 4 + i) * 36 + (ck - 2) * 16 + ln] = f2b(sc[rt * 4 + ck][i]);
            {
                bf16x8 Bv1[2];
                #pragma unroll
                for (int ct2 = 0; ct2 < 2; ++ct2)
                    Bv1[ct2] = *(const bf16x8*)&VTw[(ct2 * 16 + ln) * 72 + 32 + quad * 8];
                #pragma unroll
                for (int rt = 0; rt < 4; ++rt) {
                    bf16x8 Ap = *(const bf16x8*)&PSw[(rt * 16 + ln) * 36 + quad * 8];
                    #pragma unroll
                    for (int ct2 = 0; ct2 < 2; ++ct2)
                        avr[hp * 8 + rt * 2 + ct2] = MFMA16(Ap, Bv1[ct2], avr[hp * 8 + rt * 2 + ct2]);
                }
            }
        }

        __syncthreads();   // all waves done reading hS(h)
        // write av (wave's exact 64-col strip) -> hS
        #pragma unroll
        for (int hp = 0; hp < 2; ++hp)
            #pragma unroll
            for (int rt = 0; rt < 4; ++rt)
                #pragma unroll
                for (int ct2 = 0; ct2 < 2; ++ct2)
                    #pragma unroll
                    for (int i = 0; i < 4; ++i)
                        hS[(rt * 16 + quad * 4 + i) * 264 + nb + hp * 32 + ct2 * 16 + ln]
                            = f2b(avr[hp * 8 + rt * 2 + ct2][i]);
        __syncthreads();

        // ---- O-proj: oacc = h + bo + av @ Wo (K=256) ----
        f32x4 oacc[16];
        #pragma unroll
        for (int rt = 0; rt < 4; ++rt)
            #pragma unroll
            for (int ct = 0; ct < 4; ++ct) {
                float bz = bo_p[nb + ct * 16 + ln];
                f32x4 t = hr[rt * 4 + ct];
                t[0] += bz; t[1] += bz; t[2] += bz; t[3] += bz;
                oacc[rt * 4 + ct] = t;
            }
        #pragma unroll
        for (int ct = 0; ct < 4; ++ct) {
            bf16x8 Bo[8];
            #pragma unroll
            for (int kt = 0; kt < 8; ++kt)
                Bo[kt] = *(const bf16x8*)(WoE + (size_t)(nb + ct * 16 + ln) * 256 + kt * 32 + quad * 8);
            #pragma unroll
            for (int rt = 0; rt < 4; ++rt) {
                bf16x8 Ao[8];
                #pragma unroll
                for (int kt = 0; kt < 8; ++kt)
                    Ao[kt] = *(const bf16x8*)&hS[(rt * 16 + ln) * 264 + kt * 32 + quad * 8];
                #pragma unroll
                for (int kt = 0; kt < 8; ++kt)
                    oacc[rt * 4 + ct] = MFMA16(Ao[kt], Bo[kt], oacc[rt * 4 + ct]);
            }
        }

        // ---- LN1 -> hr, hS ----
        LN(oacc, ln1g + el * 256, ln1b + el * 256);

        // ---- FF: 8 chunks of 128 FF cols, tS double-buffered (1 barrier/chunk) ----
        f32x4 facc[16];
        {
            const float* b2_p = b2 + el * 256;
            #pragma unroll
            for (int rt = 0; rt < 4; ++rt)
                #pragma unroll
                for (int ct = 0; ct < 4; ++ct) {
                    float bz = b2_p[nb + ct * 16 + ln];
                    f32x4 t = hr[rt * 4 + ct];
                    t[0] += bz; t[1] += bz; t[2] += bz; t[3] += bz;
                    facc[rt * 4 + ct] = t;
                }
        }
        const float* b1_p = b1 + el * 1024;
        for (int ch = 0; ch < 8; ++ch) {
            const int fb = ch * 128 + wg * 32;       // wave's 32 FF cols this chunk
            unsigned short* tC = attnS + (ch & 1) * 8704;   // [64][136] dbuf
            #pragma unroll
            for (int ct2 = 0; ct2 < 2; ++ct2) {
                bf16x8 B1c[8];
                #pragma unroll
                for (int kt = 0; kt < 8; ++kt)
                    B1c[kt] = *(const bf16x8*)(W1E + (size_t)(fb + ct2 * 16 + ln) * 256 + kt * 32 + quad * 8);
                const float bz2 = b1_p[fb + ct2 * 16 + ln];
                #pragma unroll
                for (int rt = 0; rt < 4; ++rt) {
                    bf16x8 Af[8];
                    #pragma unroll
                    for (int kt = 0; kt < 8; ++kt)
                        Af[kt] = *(const bf16x8*)&hS[(rt * 16 + ln) * 264 + kt * 32 + quad * 8];
                    f32x4 c = {bz2, bz2, bz2, bz2};
                    #pragma unroll
                    for (int kt = 0; kt < 8; ++kt) c = MFMA16(Af[kt], B1c[kt], c);
                    #pragma unroll
                    for (int i = 0; i < 4; ++i)
                        tC[(rt * 16 + quad * 4 + i) * 136 + wg * 32 + ct2 * 16 + ln]
                            = f2b(fmaxf(c[i], 0.f));
                }
            }
            __syncthreads();
            // W2 partial: K=128
            #pragma unroll
            for (int ct = 0; ct < 4; ++ct) {
                bf16x8 B2c[4];
                #pragma unroll
                for (int kt2 = 0; kt2 < 4; ++kt2)
                    B2c[kt2] = *(const bf16x8*)(W2E + (size_t)(nb + ct * 16 + ln) * 1024 + ch * 128 + kt2 * 32 + quad * 8);
                #pragma unroll
                for (int rt = 0; rt < 4; ++rt) {
                    bf16x8 At[4];
                    #pragma unroll
                    for (int kt2 = 0; kt2 < 4; ++kt2)
                        At[kt2] = *(const bf16x8*)&tC[(rt * 16 + ln) * 136 + kt2 * 32 + quad * 8];
                    #pragma unroll
                    for (int kt2 = 0; kt2 < 4; ++kt2)
                        facc[rt * 4 + ct] = MFMA16(At[kt2], B2c[kt2], facc[rt * 4 + ct]);
                }
            }
            // no barrier: next W1 writes the other tS buffer
        }

        // ---- LN2 -> hr, hS ----
        LN(facc, ln2g + el * 256, ln2b + el * 256);
    }

    // ---- pooling + Wout + weighted combine ----
    {
        #pragma unroll
        for (int ct = 0; ct < 4; ++ct) {
            float s_ = 0.f;
            #pragma unroll
            for (int rt = 0; rt < 4; ++rt)
                #pragma unroll
                for (int i = 0; i < 4; ++i) s_ += hr[rt * 4 + ct][i];
            s_ += __shfl_xor(s_, 16);
            s_ += __shfl_xor(s_, 32);
            if (quad == 0) pooledS[nb + ct * 16 + ln] = s_ * (1.f / 64.f);
        }
        __syncthreads();
        if (tid < 64) {
            const float* Wout_p = Wout + (size_t)e * (256 * 64);
            float o = bout[e * 64 + tid];
            for (int c = 0; c < 256; ++c) o += pooledS[c] * Wout_p[c * 64 + tid];
            atomicAdd(&acc_out[b * 64 + tid], wgt * o);
        }
    }
}

// ---------------------------------------------------------------------------
__global__ __launch_bounds__(64) void final_ln_kernel(
    const float* __restrict__ acc_out, const float* __restrict__ on_g,
    const float* __restrict__ on_b, float* __restrict__ out)
{
    const int b = blockIdx.x;
    const int d = threadIdx.x;
    float v = acc_out[b * 64 + d];
    float s1 = v, s2 = v * v;
    #pragma unroll
    for (int st = 1; st < 64; st <<= 1) {
        s1 += __shfl_xor(s1, st, 64);
        s2 += __shfl_xor(s2, st, 64);
    }
    float m   = s1 * (1.f / 64.f);
    float var = s2 * (1.f / 64.f) - m * m;
    float rstd = rsqrtf(var + 1e-5f);
    out[b * 64 + d] = (v - m) * rstd * on_g[d] + on_b[d];
}

// ---------------------------------------------------------------------------
extern "C" void kernel_launch(void* const* d_in, const int* in_sizes, int n_in,
                              void* d_out, int out_size, void* d_ws, size_t ws_size,
                              hipStream_t stream)
{
    (void)in_sizes; (void)n_in; (void)out_size; (void)ws_size;
    const float* x    = (const float*)d_in[0];
    const float* Win  = (const float*)d_in[1];
    const float* bin_ = (const float*)d_in[2];
    const float* Wq   = (const float*)d_in[3];
    const float* bq   = (const float*)d_in[4];
    const float* Wk   = (const float*)d_in[5];
    const float* bk   = (const float*)d_in[6];
    const float* Wv   = (const float*)d_in[7];
    const float* bv   = (const float*)d_in[8];
    const float* Wo   = (const float*)d_in[9];
    const float* bo   = (const float*)d_in[10];
    const float* ln1g = (const float*)d_in[11];
    const float* ln1b = (const float*)d_in[12];
    const float* ln2g = (const float*)d_in[13];
    const float* ln2b = (const float*)d_in[14];
    const float* W1   = (const float*)d_in[15];
    const float* b1   = (const float*)d_in[16];
    const float* W2   = (const float*)d_in[17];
    const float* b2   = (const float*)d_in[18];
    const float* Wout = (const float*)d_in[19];
    const float* bout = (const float*)d_in[20];
    const float* Wg   = (const float*)d_in[21];
    const float* bg   = (const float*)d_in[22];
    const float* Wr   = (const float*)d_in[23];
    const float* br   = (const float*)d_in[24];
    const float* on_g = (const float*)d_in[25];
    const float* on_b = (const float*)d_in[26];
    float* out = (float*)d_out;

    // workspace carve-up
    char* ws = (char*)d_ws;
    float* acc_out = (float*)ws;                         // 131,072 B
    int*   cnt     = (int*)(ws + 131072);
    int*   rlist   = (int*)(ws + 131200);                // 16,384 B
    float* wlist   = (float*)(ws + 147584);              // 16,384 B
    short* WinT    = (short*)(ws + 164096);              //   524,288 B
    short* WqT     = (short*)(ws + 688384);              // 2,097,152 B
    short* WkT     = (short*)(ws + 2785536);
    short* WvT     = (short*)(ws + 4882688);
    short* WoT     = (short*)(ws + 6979840);
    short* W1T     = (short*)(ws + 9076992);             // 8,388,608 B
    short* W2T     = (short*)(ws + 17465600);            // 8,388,608 B

    // 1) zero cnt (must precede gate's atomics; separate launch for ordering)
    zero_cnt_kernel<<<1, 64, 0, stream>>>(cnt);
    // 2) convT (3136) + gate (512) + acc_out zero (32) fused: gate overlaps convT
    prep_fused_kernel<<<3680, 256, 0, stream>>>(
        Win, WinT, Wq, WqT, Wk, WkT, Wv, WvT, Wo, WoT, W1, W1T, W2, W2T,
        x, Wg, bg, cnt, rlist, wlist, acc_out);
    // 3) expert (4096) + resproj (256) fused: resproj overlaps expert
    expert_kernel<<<4352, 256, 0, stream>>>(x,
        WinT, bin_, WqT, bq, WkT, bk, WvT, bv, WoT, bo,
        ln1g, ln1b, ln2g, ln2b, W1T, b1, W2T, b2, Wout, bout, Wr, br,
        cnt, rlist, wlist, acc_out);
    // 4) final LN
    final_ln_kernel<<<512, 64, 0, stream>>>(acc_out, on_g, on_b, out);
}